// Round 2
// baseline (1866.738 us; speedup 1.0000x reference)
//
#include <hip/hip_runtime.h>
#include <hip/hip_bf16.h>
#include <math.h>

typedef unsigned int u32;
typedef unsigned long long u64;
typedef unsigned short u16;
typedef __bf16 bf16x8 __attribute__((ext_vector_type(8)));
typedef float f32x4 __attribute__((ext_vector_type(4)));

#define DEV __device__ __forceinline__

DEV u32 okey(float f){ u32 u=__float_as_uint(f); return (u & 0x80000000u) ? ~u : (u | 0x80000000u); }
DEV float unokey(u32 v){ u32 u = (v & 0x80000000u) ? (v & 0x7FFFFFFFu) : ~v; return __uint_as_float(u); }
DEV u16 f2bf(float f){ u32 u=__float_as_uint(f); u32 r = u + 0x7FFFu + ((u>>16)&1u); return (u16)(r>>16); }

DEV void stage16(const void* g, void* l){
  __builtin_amdgcn_global_load_lds((const __attribute__((address_space(1))) void*)g,
                                   (__attribute__((address_space(3))) void*)l, 16, 0, 0);
}

// ---------------- transpose-cast f32[K][N] -> bf16[N][K] ----------------
__global__ __launch_bounds__(256) void k_castT(const float* __restrict__ src, u16* __restrict__ dst, int K, int N){
  __shared__ float tile[32][33];
  int bk = blockIdx.x, bn = blockIdx.y;
  int tx = threadIdx.x, ty = threadIdx.y;
  #pragma unroll
  for (int i=0;i<4;i++){
    int r = bk*32 + ty + i*8;
    tile[ty+i*8][tx] = src[(size_t)r*N + bn*32 + tx];
  }
  __syncthreads();
  #pragma unroll
  for (int i=0;i<4;i++){
    int n = bn*32 + ty + i*8;
    dst[(size_t)n*K + bk*32 + tx] = f2bf(tile[tx][ty+i*8]);
  }
}

// ------- build BT3 [512][1024] = concat(wc^T, wb^T, 0) and bias3 -------
__global__ __launch_bounds__(256) void k_castW3(const float* __restrict__ wc, const float* __restrict__ wb,
    const float* __restrict__ bc, const float* __restrict__ bb,
    u16* __restrict__ BT3, float* __restrict__ bias3){
  int idx = blockIdx.x*256 + threadIdx.x; // 512*1024
  int n = idx >> 10, k = idx & 1023;
  float v = 0.f;
  if (n < 91) v = wc[(size_t)k*91 + n];
  else if (n < 455) v = wb[(size_t)k*364 + (n-91)];
  BT3[(size_t)n*1024 + k] = f2bf(v);
  if (idx < 512){
    float bv = 0.f;
    if (idx < 91) bv = bc[idx]; else if (idx < 455) bv = bb[idx-91];
    bias3[idx] = bv;
  }
}

// ---------------- per-(batch,level) exact top-k, sorted ----------------
__global__ __launch_bounds__(256) void k_topk(const float* s2,const float* s3,const float* s4,const float* s5,const float* s6,
    u32* __restrict__ selIdx, float* __restrict__ sRaw, float* __restrict__ sPre){
  constexpr int Nls[5] = {209664,52416,13104,3276,819};
  constexpr int nss[5] = {1000,1000,1000,1000,819};
  int li = blockIdx.x % 5, b = blockIdx.x / 5;
  const float* sp = li==0?s2: li==1?s3: li==2?s4: li==3?s5: s6;
  const int Nl = Nls[li], ns = nss[li];
  sp += (size_t)b*Nl;
  __shared__ u32 hist[256];
  __shared__ u32 sh_prefix, sh_rank, sh_cnt;
  __shared__ u64 keys[2048];
  int tid = threadIdx.x;
  if (tid==0){ sh_prefix=0u; sh_rank=(u32)ns; }
  __syncthreads();
  u32 prefix = 0;
  for (int p=0;p<4;p++){
    hist[tid]=0; __syncthreads();
    int sh_hi = 8*(4-p), sh_lo = 8*(3-p);
    for (int i=tid;i<Nl;i+=256){
      u32 u = okey(sp[i]);
      if (p==0 || (u >> sh_hi) == prefix) atomicAdd(&hist[(u >> sh_lo) & 255u], 1u);
    }
    __syncthreads();
    if (tid==0){
      u32 r2 = sh_rank, cum=0; int bin=255;
      for (;bin>0;bin--){ u32 c=hist[bin]; if (cum + c >= r2) break; cum += c; }
      sh_rank = r2 - cum;
      sh_prefix = (sh_prefix<<8) | (u32)bin;
    }
    __syncthreads();
    prefix = sh_prefix;
    __syncthreads();
  }
  if (tid==0) sh_cnt=0u;
  __syncthreads();
  u32 T = sh_prefix;
  for (int i=tid;i<Nl;i+=256){
    u32 u = okey(sp[i]);
    if (u >= T){
      u32 pos = atomicAdd(&sh_cnt,1u);
      if (pos < 2048u) keys[pos] = ((u64)u<<32) | (u32)(~(u32)i);
    }
  }
  __syncthreads();
  u32 cnt = sh_cnt; if (cnt > 2048u) cnt = 2048u;
  for (u32 i=cnt+(u32)tid; i<2048u; i+=256u) keys[i]=0ull;
  for (int k2=2;k2<=2048;k2<<=1){
    for (int j2=k2>>1;j2>=1;j2>>=1){
      __syncthreads();
      for (int t=tid;t<1024;t+=256){
        int i1 = ((t & ~(j2-1))<<1) | (t & (j2-1));
        int i2 = i1 | j2;
        u64 a=keys[i1], bb2=keys[i2];
        bool asc = (i1 & k2) != 0;
        bool sw = asc ? (a>bb2) : (a<bb2);
        if (sw){ keys[i1]=bb2; keys[i2]=a; }
      }
    }
  }
  __syncthreads();
  int base = b*4819 + li*1000;
  for (int r=tid;r<ns;r+=256){
    u64 kk = keys[r];
    u32 idx = ~((u32)kk);
    float scv = unokey((u32)(kk>>32));
    selIdx[base+r] = idx;
    sRaw[base+r] = scv;
    sPre[base+r] = (float)(1.0/(1.0+exp(-(double)scv)));
  }
}

// ---------------- decode + clip selected boxes ----------------
__global__ __launch_bounds__(256) void k_decode(const u32* __restrict__ selIdx,
    const float* a2,const float* a3,const float* a4,const float* a5,const float* a6,
    const float* d2,const float* d3,const float* d4,const float* d5,const float* d6,
    const float* __restrict__ info, float* __restrict__ boxes){
  constexpr int Nls[5] = {209664,52416,13104,3276,819};
  int g = blockIdx.x*256 + threadIdx.x;
  if (g >= 9638) return;
  int b = g/4819, r = g%4819;
  int li = r/1000; if (li>4) li=4;
  u32 idx = selIdx[g];
  const float* anc = li==0?a2: li==1?a3: li==2?a4: li==3?a5: a6;
  const float* del = li==0?d2: li==1?d3: li==2?d4: li==3?d5: d6;
  const float* aa = anc + (size_t)idx*4;
  const float* dd = del + ((size_t)b*Nls[li] + idx)*4;
  float ah=aa[2]-aa[0], aw=aa[3]-aa[1];
  float acy=aa[0]+0.5f*ah, acx=aa[1]+0.5f*aw;
  const float CLIPV = 4.135166556742356f;
  float dh=fminf(dd[2],CLIPV), dw=fminf(dd[3],CLIPV);
  float cy=acy+dd[0]*ah, cx=acx+dd[1]*aw;
  float hh=ah*expf(dh), ww=aw*expf(dw);
  float hmax=info[b*5+0], wmax=info[b*5+1];
  float vy1=fminf(fmaxf(cy-0.5f*hh,0.f),hmax);
  float vx1=fminf(fmaxf(cx-0.5f*ww,0.f),wmax);
  float vy2=fminf(fmaxf(cy+0.5f*hh,0.f),hmax);
  float vx2=fminf(fmaxf(cx+0.5f*ww,0.f),wmax);
  ((float4*)boxes)[g] = make_float4(vy1,vx1,vy2,vx2);
}

// ---------------- NMS suppression bitmask matrix ----------------
__global__ __launch_bounds__(256) void k_nms_mask(const float* __restrict__ boxes, u64* __restrict__ masks){
  constexpr int nss[5] = {1000,1000,1000,1000,819};
  int rg = blockIdx.x;
  int b = rg/4819, r = rg%4819;
  int li = r/1000; if (li>4) li=4;
  int i = r - li*1000;
  int n = nss[li];
  int gb = b*4819 + li*1000;
  __shared__ float4 sbi;
  if (threadIdx.x==0) sbi = ((const float4*)boxes)[gb+i];
  __syncthreads();
  float4 bi = sbi;
  float ai = fmaxf(bi.z-bi.x,0.f)*fmaxf(bi.w-bi.y,0.f);
  int t = threadIdx.x, wv = t>>6, lane = t&63;
  #pragma unroll
  for (int it=0; it<4; ++it){
    int jj = it*256 + wv*64 + lane;
    bool c = false;
    if (jj < n && jj > i){
      float4 bj = ((const float4*)boxes)[gb+jj];
      float aj = fmaxf(bj.z-bj.x,0.f)*fmaxf(bj.w-bj.y,0.f);
      float yy1=fmaxf(bi.x,bj.x), xx1=fmaxf(bi.y,bj.y);
      float yy2=fminf(bi.z,bj.z), xx2=fminf(bi.w,bj.w);
      float inter=fmaxf(yy2-yy1,0.f)*fmaxf(xx2-xx1,0.f);
      float iou = inter/(ai+aj-inter+1e-8f);
      c = iou > 0.7f;
    }
    u64 m = __ballot(c);
    if (lane==0) masks[(size_t)rg*16 + it*4 + wv] = m;
  }
}

// ---------------- serial greedy reduce (one wave per group) ----------------
__global__ __launch_bounds__(64) void k_nms_reduce(const u64* __restrict__ masks, const float* __restrict__ sPre, float* __restrict__ allS){
  constexpr int nss[5] = {1000,1000,1000,1000,819};
  int li = blockIdx.x % 5, b = blockIdx.x / 5;
  int n = nss[li];
  int gb = b*4819 + li*1000;
  int lane = threadIdx.x;
  u64 removed = 0ull;
  u64 cur = (lane<16) ? masks[(size_t)gb*16 + lane] : 0ull;
  for (int i=0;i<n;i++){
    u64 nxt = (lane<16 && i+1<n) ? masks[(size_t)(gb+i+1)*16 + lane] : 0ull;
    int wi = i>>6;
    u64 rw = __shfl(removed, wi);
    bool kept = ((rw >> (i & 63)) & 1ull) == 0ull;
    if (kept) removed |= cur;
    cur = nxt;
  }
  if (lane < 16){
    for (int q=0; q<64; ++q){
      int jj = lane*64 + q;
      if (jj < n){
        bool kp = ((removed >> q) & 1ull) == 0ull;
        allS[gb+jj] = kp ? sPre[gb+jj] : -1.0f;
      }
    }
  }
}

// ---------------- final global top-1000 (sorted), write rois + rs ----------------
__global__ __launch_bounds__(1024) void k_final(const float* __restrict__ allS, const float* __restrict__ sRaw,
   const float* __restrict__ boxes, float* __restrict__ outR, float* __restrict__ outS){
  __shared__ u64 keys[8192];
  int b = blockIdx.x, tid = threadIdx.x;
  for (int e=tid;e<8192;e+=1024){
    u64 kk = 0ull;
    if (e < 4819){
      float v = allS[b*4819+e];
      u32 ie = (~(u32)e) & 0x7FFFFFFFu;
      if (v > -0.5f) kk = (1ull<<63) | ((u64)okey(sRaw[b*4819+e])<<31) | (u64)ie;
      else           kk = (u64)ie;
    }
    keys[e] = kk;
  }
  for (int k2=2;k2<=8192;k2<<=1){
    for (int j2=k2>>1;j2>=1;j2>>=1){
      __syncthreads();
      for (int t=tid;t<4096;t+=1024){
        int i1 = ((t & ~(j2-1))<<1) | (t & (j2-1));
        int i2 = i1 | j2;
        u64 a=keys[i1], bb2=keys[i2];
        bool asc = (i1 & k2) != 0;
        bool sw = asc ? (a>bb2) : (a<bb2);
        if (sw){ keys[i1]=bb2; keys[i2]=a; }
      }
    }
  }
  __syncthreads();
  for (int r=tid;r<1000;r+=1024){
    u64 kk = keys[r];
    u32 ieF = (u32)kk & 0x7FFFFFFFu;
    int e = (int)((~ieF) & 0x7FFFFFFFu);
    outS[b*1000+r] = allS[b*4819+e];
    ((float4*)outR)[b*1000+r] = ((const float4*)boxes)[b*4819+e];
  }
}

// ---------------- ROI align -> bf16 A matrix [2048][12544] ----------------
__global__ __launch_bounds__(256) void k_roi(const float* __restrict__ rois,
    const float* f2,const float* f3,const float* f4,const float* f5,const float* f6,
    u16* __restrict__ Amat){
  constexpr int Hs[5]={208,104,52,26,13};
  constexpr int Wsv[5]={336,168,84,42,21};
  constexpr float strd[5]={4.f,8.f,16.f,32.f,64.f};
  int g = blockIdx.x;
  u16* Arow = Amat + (size_t)g*12544;
  int tid = threadIdx.x;
  if (g >= 2000){
    for (int i=tid;i<12544;i+=256) Arow[i]=0;
    return;
  }
  int b = g/1000;
  const float* box = rois + (size_t)g*4;
  float y1=box[0], x1=box[1], y2=box[2], x2=box[3];
  float area = fmaxf(y2-y1,0.f)*fmaxf(x2-x1,0.f);
  int lvl = (int)floorf(4.f + log2f(sqrtf(area)/224.f + 1e-8f));
  lvl = lvl < 2 ? 2 : (lvl > 6 ? 6 : lvl);
  int li = lvl-2;
  int Hl=Hs[li], Wl=Wsv[li]; float sc=strd[li];
  __shared__ float swy[14], swx[14];
  __shared__ int sy0[14], sy1[14], sx0[14], sx1[14];
  if (tid < 14){
    float t = (float)tid / 13.f;
    float ys = (y1 + (y2-y1)*t)/sc; ys = fminf(fmaxf(ys,0.f),(float)(Hl-1));
    int yy0 = (int)floorf(ys);
    sy0[tid]=yy0; sy1[tid]=(yy0+1>Hl-1)?(Hl-1):(yy0+1); swy[tid]=ys-(float)yy0;
    float xs = (x1 + (x2-x1)*t)/sc; xs = fminf(fmaxf(xs,0.f),(float)(Wl-1));
    int xx0 = (int)floorf(xs);
    sx0[tid]=xx0; sx1[tid]=(xx0+1>Wl-1)?(Wl-1):(xx0+1); swx[tid]=xs-(float)xx0;
  }
  __syncthreads();
  const float* fb = (li==0?f2: li==1?f3: li==2?f4: li==3?f5: f6) + (size_t)b*Hl*Wl*256;
  int c = tid;
  for (int cell=0; cell<49; ++cell){
    int cy=cell/7, cx=cell%7;
    float accv=0.f;
    #pragma unroll
    for (int sy=0;sy<2;sy++){
      int iy=cy*2+sy;
      float wy=swy[iy];
      const float* r0 = fb + (size_t)sy0[iy]*Wl*256;
      const float* r1 = fb + (size_t)sy1[iy]*Wl*256;
      #pragma unroll
      for (int sx=0;sx<2;sx++){
        int ix=cx*2+sx;
        float wx=swx[ix];
        int xa=sx0[ix]*256+c, xb=sx1[ix]*256+c;
        float v00=r0[xa], v01=r0[xb], v10=r1[xa], v11=r1[xb];
        accv += v00*(1.f-wy)*(1.f-wx) + v01*(1.f-wy)*wx + v10*wy*(1.f-wx) + v11*wy*wx;
      }
    }
    Arow[cell*256+c] = f2bf(accv*0.25f);
  }
}

// ---------------- bf16 MFMA GEMM: C[M][N] = A[M][K] * BT[N][K]^T ----------------
// 128x64 tile, 4 waves (2x2), 16x16x32 bf16 MFMA, global_load_lds staging,
// slot-XOR LDS swizzle (2-way bank aliasing only), XCD-bijective block swizzle.
template<int EPI>
__global__ __launch_bounds__(256) void k_gemm(const u16* __restrict__ A, const u16* __restrict__ BT,
    const float* __restrict__ bias, u16* __restrict__ Hh,
    float* __restrict__ out0, float* __restrict__ out1,
    int K, int nTileN, int nk){
  __shared__ __align__(16) char lds[24576];
  char* ldsA = lds;
  char* ldsB = lds + 16384;
  int bid = blockIdx.x;
  int nwg = gridDim.x;
  int q = nwg >> 3;
  int wgid = (bid & 7)*q + (bid >> 3);
  int mi = wgid / nTileN, ni = wgid % nTileN;
  int m0 = mi*128, n0 = ni*64;
  int tid = threadIdx.x;
  int w = tid >> 6, lane = tid & 63;
  int wm = w >> 1, wn = w & 1;
  int lo4 = lane & 15, hi2 = lane >> 4, xr = lane & 7;
  f32x4 acc[4][2];
  #pragma unroll
  for (int m=0;m<4;m++)
    #pragma unroll
    for (int n=0;n<2;n++) acc[m][n] = (f32x4){0.f,0.f,0.f,0.f};
  int wavebase = tid & ~63;
  for (int kt=0; kt<nk; ++kt){
    const u16* Ak = A + (size_t)kt*64;
    const u16* Bk = BT + (size_t)kt*64;
    #pragma unroll
    for (int c=0;c<4;c++){
      int flat = c*256 + tid;
      int prow = flat >> 3;
      int ls = (flat & 7) ^ (prow & 7);
      stage16(Ak + (size_t)(m0+prow)*K + ls*8, ldsA + (size_t)(c*256 + wavebase)*16);
    }
    #pragma unroll
    for (int c=0;c<2;c++){
      int flat = c*256 + tid;
      int prow = flat >> 3;
      int ls = (flat & 7) ^ (prow & 7);
      stage16(Bk + (size_t)(n0+prow)*K + ls*8, ldsB + (size_t)(c*256 + wavebase)*16);
    }
    __syncthreads();
    bf16x8 af[2][4], bfv[2][2];
    #pragma unroll
    for (int ks=0;ks<2;ks++){
      int sA = (((ks*4 + hi2) ^ xr) << 4);
      #pragma unroll
      for (int m=0;m<4;m++) af[ks][m] = *(const bf16x8*)(ldsA + (wm*64 + m*16 + lo4)*128 + sA);
      #pragma unroll
      for (int n=0;n<2;n++) bfv[ks][n] = *(const bf16x8*)(ldsB + (wn*32 + n*16 + lo4)*128 + sA);
    }
    #pragma unroll
    for (int ks=0;ks<2;ks++)
      #pragma unroll
      for (int m=0;m<4;m++)
        #pragma unroll
        for (int n=0;n<2;n++)
          acc[m][n] = __builtin_amdgcn_mfma_f32_16x16x32_bf16(af[ks][m], bfv[ks][n], acc[m][n], 0,0,0);
    __syncthreads();
  }
  #pragma unroll
  for (int m=0;m<4;m++){
    #pragma unroll
    for (int n=0;n<2;n++){
      int col = n0 + wn*32 + n*16 + lo4;
      float bv = bias[col];
      int rbase = m0 + wm*64 + m*16 + hi2*4;
      #pragma unroll
      for (int j=0;j<4;j++){
        float v = acc[m][n][j] + bv;
        int rr = rbase + j;
        if (EPI == 0){
          v = fmaxf(v, 0.f);
          Hh[(size_t)rr*1024 + col] = f2bf(v);
        } else {
          if (rr < 2000){
            if (col < 91) out0[(size_t)rr*91 + col] = v;
            else if (col < 455) out1[(size_t)rr*364 + (col-91)] = v;
          }
        }
      }
    }
  }
}

extern "C" void kernel_launch(void* const* d_in, const int* in_sizes, int n_in,
                              void* d_out, int out_size, void* d_ws, size_t ws_size,
                              hipStream_t stream) {
  (void)in_sizes; (void)n_in; (void)out_size; (void)ws_size;
  const float *f[5], *s[5], *dl[5], *an[5];
  for (int i=0;i<5;i++){
    f[i]  = (const float*)d_in[4*i+0];
    s[i]  = (const float*)d_in[4*i+1];
    dl[i] = (const float*)d_in[4*i+2];
    an[i] = (const float*)d_in[4*i+3];
  }
  const float* info = (const float*)d_in[20];
  const float* w1 = (const float*)d_in[21];
  const float* b1 = (const float*)d_in[22];
  const float* w2 = (const float*)d_in[23];
  const float* b2 = (const float*)d_in[24];
  const float* wc = (const float*)d_in[25];
  const float* bc = (const float*)d_in[26];
  const float* wb = (const float*)d_in[27];
  const float* bbp= (const float*)d_in[28];

  char* base = (char*)d_ws; size_t off = 0;
  auto alloc = [&](size_t bytes)->char*{ char* p = base + off; off = (off + bytes + 255) & ~(size_t)255; return p; };
  u16*  BT1   = (u16*)alloc(1024ull*12544*2);
  u16*  BT2   = (u16*)alloc(1024ull*1024*2);
  u16*  BT3   = (u16*)alloc(512ull*1024*2);
  float* bias3= (float*)alloc(512*4);
  u16*  Amat  = (u16*)alloc(2048ull*12544*2);
  u16*  h1    = (u16*)alloc(2048ull*1024*2);
  u16*  h2    = (u16*)alloc(2048ull*1024*2);
  u32*  selIdx= (u32*)alloc(9638ull*4);
  float* sRaw = (float*)alloc(9638ull*4);
  float* sPre = (float*)alloc(9638ull*4);
  float* boxes= (float*)alloc(9638ull*16);
  float* allS = (float*)alloc(9638ull*4);
  u64*  masks = (u64*)alloc(9638ull*16*8);

  float* out0 = (float*)d_out;           // (2,1000,91)
  float* out1 = out0 + 182000;           // (2,1000,364)
  float* outR = out0 + 910000;           // (2,1000,4)
  float* outS = out0 + 918000;           // (2,1000)

  k_castT<<<dim3(392,32), dim3(32,8), 0, stream>>>(w1, BT1, 12544, 1024);
  k_castT<<<dim3(32,32),  dim3(32,8), 0, stream>>>(w2, BT2, 1024, 1024);
  k_castW3<<<dim3(2048), dim3(256), 0, stream>>>(wc, wb, bc, bbp, BT3, bias3);
  k_topk<<<dim3(10), dim3(256), 0, stream>>>(s[0],s[1],s[2],s[3],s[4], selIdx, sRaw, sPre);
  k_decode<<<dim3(38), dim3(256), 0, stream>>>(selIdx,
      an[0],an[1],an[2],an[3],an[4], dl[0],dl[1],dl[2],dl[3],dl[4], info, boxes);
  k_nms_mask<<<dim3(9638), dim3(256), 0, stream>>>(boxes, masks);
  k_nms_reduce<<<dim3(10), dim3(64), 0, stream>>>(masks, sPre, allS);
  k_final<<<dim3(2), dim3(1024), 0, stream>>>(allS, sRaw, boxes, outR, outS);
  k_roi<<<dim3(2048), dim3(256), 0, stream>>>(outR, f[0],f[1],f[2],f[3],f[4], Amat);
  k_gemm<0><<<dim3(256), dim3(256), 0, stream>>>(Amat, BT1, b1, h1, nullptr, nullptr, 12544, 16, 196);
  k_gemm<0><<<dim3(256), dim3(256), 0, stream>>>(h1,   BT2, b2, h2, nullptr, nullptr, 1024, 16, 16);
  k_gemm<1><<<dim3(128), dim3(256), 0, stream>>>(h2,   BT3, bias3, nullptr, out0, out1, 1024, 8, 16);
}

// Round 3
// 1096.128 us; speedup vs baseline: 1.7030x; 1.7030x over previous
//
#include <hip/hip_runtime.h>
#include <hip/hip_bf16.h>
#include <math.h>

typedef unsigned int u32;
typedef unsigned long long u64;
typedef unsigned short u16;
typedef __bf16 bf16x8 __attribute__((ext_vector_type(8)));
typedef float f32x4 __attribute__((ext_vector_type(4)));

#define DEV __device__ __forceinline__

DEV u32 okey(float f){ u32 u=__float_as_uint(f); return (u & 0x80000000u) ? ~u : (u | 0x80000000u); }
DEV float unokey(u32 v){ u32 u = (v & 0x80000000u) ? (v & 0x7FFFFFFFu) : ~v; return __uint_as_float(u); }
DEV u16 f2bf(float f){ u32 u=__float_as_uint(f); u32 r = u + 0x7FFFu + ((u>>16)&1u); return (u16)(r>>16); }

DEV void stage16(const void* g, void* l){
  __builtin_amdgcn_global_load_lds((const __attribute__((address_space(1))) void*)g,
                                   (__attribute__((address_space(3))) void*)l, 16, 0, 0);
}

__constant__ const int c_Nls[5] = {209664,52416,13104,3276,819};
__constant__ const int c_nss[5] = {1000,1000,1000,1000,819};

// ---------------- transpose-cast f32[K][N] -> bf16[N][K] ----------------
__global__ __launch_bounds__(256) void k_castT(const float* __restrict__ src, u16* __restrict__ dst, int K, int N){
  __shared__ float tile[32][33];
  int bk = blockIdx.x, bn = blockIdx.y;
  int tx = threadIdx.x, ty = threadIdx.y;
  #pragma unroll
  for (int i=0;i<4;i++){
    int r = bk*32 + ty + i*8;
    tile[ty+i*8][tx] = src[(size_t)r*N + bn*32 + tx];
  }
  __syncthreads();
  #pragma unroll
  for (int i=0;i<4;i++){
    int n = bn*32 + ty + i*8;
    dst[(size_t)n*K + bk*32 + tx] = f2bf(tile[tx][ty+i*8]);
  }
}

// ------- build BT3 [512][1024] = concat(wc^T, wb^T, 0) and bias3 -------
__global__ __launch_bounds__(256) void k_castW3(const float* __restrict__ wc, const float* __restrict__ wb,
    const float* __restrict__ bc, const float* __restrict__ bb,
    u16* __restrict__ BT3, float* __restrict__ bias3){
  int idx = blockIdx.x*256 + threadIdx.x; // 512*1024
  int n = idx >> 10, k = idx & 1023;
  float v = 0.f;
  if (n < 91) v = wc[(size_t)k*91 + n];
  else if (n < 455) v = wb[(size_t)k*364 + (n-91)];
  BT3[(size_t)n*1024 + k] = f2bf(v);
  if (idx < 512){
    float bv = 0.f;
    if (idx < 91) bv = bc[idx]; else if (idx < 455) bv = bb[idx-91];
    bias3[idx] = bv;
  }
}

// ---------------- top-k stage 0: zero hist + counters ----------------
__global__ __launch_bounds__(256) void k_zero(u32* __restrict__ p, int n){
  int i = blockIdx.x*256 + threadIdx.x;
  if (i < n) p[i] = 0u;
}

// ---------------- top-k stage 1: 11-bit histogram, 64 blocks/group ----------------
__global__ __launch_bounds__(256) void k_hist(const float* s2,const float* s3,const float* s4,const float* s5,const float* s6,
    u32* __restrict__ histG){
  int grp = blockIdx.x >> 6, blk = blockIdx.x & 63;
  int li = grp % 5, b = grp / 5;
  const float* sp = (li==0?s2: li==1?s3: li==2?s4: li==3?s5: s6) + (size_t)b*c_Nls[li];
  int Nl = c_Nls[li];
  __shared__ u32 h[2048];
  int tid = threadIdx.x;
  for (int i=tid;i<2048;i+=256) h[i]=0u;
  __syncthreads();
  for (int i = blk*256 + tid; i < Nl; i += 64*256){
    u32 u = okey(sp[i]);
    atomicAdd(&h[u >> 21], 1u);
  }
  __syncthreads();
  u32* hg = histG + grp*2048;
  for (int i=tid;i<2048;i+=256){ u32 v=h[i]; if (v) atomicAdd(&hg[i], v); }
}

// ---------------- top-k stage 2: find threshold bin ----------------
__global__ __launch_bounds__(256) void k_select(const u32* __restrict__ histG, u32* __restrict__ thrG){
  int grp = blockIdx.x;
  int li = grp % 5;
  u32 ns = (u32)c_nss[li];
  const u32* hg = histG + grp*2048;
  __shared__ u32 part[256];
  int tid = threadIdx.x;
  int hibase = 2047 - tid*8;
  u32 s = 0;
  #pragma unroll
  for (int j=0;j<8;j++) s += hg[hibase - j];
  part[tid] = s;
  __syncthreads();
  if (tid==0){
    u32 cum = 0; int t;
    for (t=0;t<255;t++){ if (cum + part[t] >= ns) break; cum += part[t]; }
    int hb = 2047 - t*8;
    int bin = hb - 7;
    for (int j=0;j<8;j++){ u32 c = hg[hb-j]; if (cum + c >= ns){ bin = hb-j; break; } cum += c; }
    thrG[grp] = (u32)bin;
  }
}

// ---------------- top-k stage 3: gather candidates >= threshold bin ----------------
__global__ __launch_bounds__(256) void k_gather(const float* s2,const float* s3,const float* s4,const float* s5,const float* s6,
    const u32* __restrict__ thrG, u32* __restrict__ cntG, u64* __restrict__ cand){
  int grp = blockIdx.x >> 6, blk = blockIdx.x & 63;
  int li = grp % 5, b = grp / 5;
  const float* sp = (li==0?s2: li==1?s3: li==2?s4: li==3?s5: s6) + (size_t)b*c_Nls[li];
  int Nl = c_Nls[li];
  u32 T = thrG[grp] << 21;
  for (int i = blk*256 + threadIdx.x; i < Nl; i += 64*256){
    u32 u = okey(sp[i]);
    if (u >= T){
      u32 pos = atomicAdd(&cntG[grp], 1u);
      if (pos < 2048u) cand[(size_t)grp*2048 + pos] = ((u64)u<<32) | (u32)(~(u32)i);
    }
  }
}

// ---------------- top-k stage 4: bitonic sort candidates, emit ----------------
__global__ __launch_bounds__(256) void k_sortC(const u64* __restrict__ cand, const u32* __restrict__ cntG,
    u32* __restrict__ selIdx, float* __restrict__ sRaw, float* __restrict__ sPre){
  int grp = blockIdx.x;
  int li = grp % 5, b = grp / 5;
  int ns = c_nss[li];
  __shared__ u64 keys[2048];
  int tid = threadIdx.x;
  u32 cnt = cntG[grp]; if (cnt > 2048u) cnt = 2048u;
  for (int i=tid;i<2048;i+=256) keys[i] = (i < (int)cnt) ? cand[(size_t)grp*2048 + i] : 0ull;
  for (int k2=2;k2<=2048;k2<<=1){
    for (int j2=k2>>1;j2>=1;j2>>=1){
      __syncthreads();
      for (int t=tid;t<1024;t+=256){
        int i1 = ((t & ~(j2-1))<<1) | (t & (j2-1));
        int i2 = i1 | j2;
        u64 a=keys[i1], bb2=keys[i2];
        bool asc = (i1 & k2) != 0;
        bool sw = asc ? (a>bb2) : (a<bb2);
        if (sw){ keys[i1]=bb2; keys[i2]=a; }
      }
    }
  }
  __syncthreads();
  int base = b*4819 + li*1000;
  for (int r=tid;r<ns;r+=256){
    u64 kk = keys[r];
    u32 idx = ~((u32)kk);
    float scv = unokey((u32)(kk>>32));
    selIdx[base+r] = idx;
    sRaw[base+r] = scv;
    sPre[base+r] = (float)(1.0/(1.0+exp(-(double)scv)));
  }
}

// ---------------- decode + clip selected boxes ----------------
__global__ __launch_bounds__(256) void k_decode(const u32* __restrict__ selIdx,
    const float* a2,const float* a3,const float* a4,const float* a5,const float* a6,
    const float* d2,const float* d3,const float* d4,const float* d5,const float* d6,
    const float* __restrict__ info, float* __restrict__ boxes){
  int g = blockIdx.x*256 + threadIdx.x;
  if (g >= 9638) return;
  int b = g/4819, r = g%4819;
  int li = r/1000; if (li>4) li=4;
  u32 idx = selIdx[g];
  const float* anc = li==0?a2: li==1?a3: li==2?a4: li==3?a5: a6;
  const float* del = li==0?d2: li==1?d3: li==2?d4: li==3?d5: d6;
  const float* aa = anc + (size_t)idx*4;
  const float* dd = del + ((size_t)b*c_Nls[li] + idx)*4;
  float ah=aa[2]-aa[0], aw=aa[3]-aa[1];
  float acy=aa[0]+0.5f*ah, acx=aa[1]+0.5f*aw;
  const float CLIPV = 4.135166556742356f;
  float dh=fminf(dd[2],CLIPV), dw=fminf(dd[3],CLIPV);
  float cy=acy+dd[0]*ah, cx=acx+dd[1]*aw;
  float hh=ah*expf(dh), ww=aw*expf(dw);
  float hmax=info[b*5+0], wmax=info[b*5+1];
  float vy1=fminf(fmaxf(cy-0.5f*hh,0.f),hmax);
  float vx1=fminf(fmaxf(cx-0.5f*ww,0.f),wmax);
  float vy2=fminf(fmaxf(cy+0.5f*hh,0.f),hmax);
  float vx2=fminf(fmaxf(cx+0.5f*ww,0.f),wmax);
  ((float4*)boxes)[g] = make_float4(vy1,vx1,vy2,vx2);
}

// ---------------- NMS suppression bitmask matrix ----------------
__global__ __launch_bounds__(256) void k_nms_mask(const float* __restrict__ boxes, u64* __restrict__ masks){
  int rg = blockIdx.x;
  int b = rg/4819, r = rg%4819;
  int li = r/1000; if (li>4) li=4;
  int i = r - li*1000;
  int n = c_nss[li];
  int gb = b*4819 + li*1000;
  __shared__ float4 sbi;
  if (threadIdx.x==0) sbi = ((const float4*)boxes)[gb+i];
  __syncthreads();
  float4 bi = sbi;
  float ai = fmaxf(bi.z-bi.x,0.f)*fmaxf(bi.w-bi.y,0.f);
  int t = threadIdx.x, wv = t>>6, lane = t&63;
  #pragma unroll
  for (int it=0; it<4; ++it){
    int jj = it*256 + wv*64 + lane;
    bool c = false;
    if (jj < n && jj > i){
      float4 bj = ((const float4*)boxes)[gb+jj];
      float aj = fmaxf(bj.z-bj.x,0.f)*fmaxf(bj.w-bj.y,0.f);
      float yy1=fmaxf(bi.x,bj.x), xx1=fmaxf(bi.y,bj.y);
      float yy2=fminf(bi.z,bj.z), xx2=fminf(bi.w,bj.w);
      float inter=fmaxf(yy2-yy1,0.f)*fmaxf(xx2-xx1,0.f);
      float iou = inter/(ai+aj-inter+1e-8f);
      c = iou > 0.7f;
    }
    u64 m = __ballot(c);
    if (lane==0) masks[(size_t)rg*16 + it*4 + wv] = m;
  }
}

// ---------------- serial greedy reduce (one wave per group) ----------------
__global__ __launch_bounds__(64) void k_nms_reduce(const u64* __restrict__ masks, const float* __restrict__ sPre, float* __restrict__ allS){
  int li = blockIdx.x % 5, b = blockIdx.x / 5;
  int n = c_nss[li];
  int gb = b*4819 + li*1000;
  int lane = threadIdx.x;
  u64 removed = 0ull;
  u64 cur = (lane<16) ? masks[(size_t)gb*16 + lane] : 0ull;
  for (int i=0;i<n;i++){
    u64 nxt = (lane<16 && i+1<n) ? masks[(size_t)(gb+i+1)*16 + lane] : 0ull;
    int wi = i>>6;
    u64 rw = __shfl(removed, wi);
    bool kept = ((rw >> (i & 63)) & 1ull) == 0ull;
    if (kept) removed |= cur;
    cur = nxt;
  }
  if (lane < 16){
    for (int q=0; q<64; ++q){
      int jj = lane*64 + q;
      if (jj < n){
        bool kp = ((removed >> q) & 1ull) == 0ull;
        allS[gb+jj] = kp ? sPre[gb+jj] : -1.0f;
      }
    }
  }
}

// ---------------- final global top-1000 (sorted), write rois + rs ----------------
__global__ __launch_bounds__(1024) void k_final(const float* __restrict__ allS, const float* __restrict__ sRaw,
   const float* __restrict__ boxes, float* __restrict__ outR, float* __restrict__ outS){
  __shared__ u64 keys[8192];
  int b = blockIdx.x, tid = threadIdx.x;
  for (int e=tid;e<8192;e+=1024){
    u64 kk = 0ull;
    if (e < 4819){
      float v = allS[b*4819+e];
      u32 ie = (~(u32)e) & 0x7FFFFFFFu;
      if (v > -0.5f) kk = (1ull<<63) | ((u64)okey(sRaw[b*4819+e])<<31) | (u64)ie;
      else           kk = (u64)ie;
    }
    keys[e] = kk;
  }
  for (int k2=2;k2<=8192;k2<<=1){
    for (int j2=k2>>1;j2>=1;j2>>=1){
      __syncthreads();
      for (int t=tid;t<4096;t+=1024){
        int i1 = ((t & ~(j2-1))<<1) | (t & (j2-1));
        int i2 = i1 | j2;
        u64 a=keys[i1], bb2=keys[i2];
        bool asc = (i1 & k2) != 0;
        bool sw = asc ? (a>bb2) : (a<bb2);
        if (sw){ keys[i1]=bb2; keys[i2]=a; }
      }
    }
  }
  __syncthreads();
  for (int r=tid;r<1000;r+=1024){
    u64 kk = keys[r];
    u32 ieF = (u32)kk & 0x7FFFFFFFu;
    int e = (int)((~ieF) & 0x7FFFFFFFu);
    outS[b*1000+r] = allS[b*4819+e];
    ((float4*)outR)[b*1000+r] = ((const float4*)boxes)[b*4819+e];
  }
}

// ---------------- ROI align -> bf16 A matrix [2048][12544] ----------------
__global__ __launch_bounds__(256) void k_roi(const float* __restrict__ rois,
    const float* f2,const float* f3,const float* f4,const float* f5,const float* f6,
    u16* __restrict__ Amat){
  constexpr int Hs[5]={208,104,52,26,13};
  constexpr int Wsv[5]={336,168,84,42,21};
  constexpr float strd[5]={4.f,8.f,16.f,32.f,64.f};
  int g = blockIdx.x;
  u16* Arow = Amat + (size_t)g*12544;
  int tid = threadIdx.x;
  if (g >= 2000){
    for (int i=tid;i<12544;i+=256) Arow[i]=0;
    return;
  }
  int b = g/1000;
  const float* box = rois + (size_t)g*4;
  float y1=box[0], x1=box[1], y2=box[2], x2=box[3];
  float area = fmaxf(y2-y1,0.f)*fmaxf(x2-x1,0.f);
  int lvl = (int)floorf(4.f + log2f(sqrtf(area)/224.f + 1e-8f));
  lvl = lvl < 2 ? 2 : (lvl > 6 ? 6 : lvl);
  int li = lvl-2;
  int Hl=Hs[li], Wl=Wsv[li]; float sc=strd[li];
  __shared__ float swy[14], swx[14];
  __shared__ int sy0[14], sy1[14], sx0[14], sx1[14];
  if (tid < 14){
    float t = (float)tid / 13.f;
    float ys = (y1 + (y2-y1)*t)/sc; ys = fminf(fmaxf(ys,0.f),(float)(Hl-1));
    int yy0 = (int)floorf(ys);
    sy0[tid]=yy0; sy1[tid]=(yy0+1>Hl-1)?(Hl-1):(yy0+1); swy[tid]=ys-(float)yy0;
    float xs = (x1 + (x2-x1)*t)/sc; xs = fminf(fmaxf(xs,0.f),(float)(Wl-1));
    int xx0 = (int)floorf(xs);
    sx0[tid]=xx0; sx1[tid]=(xx0+1>Wl-1)?(Wl-1):(xx0+1); swx[tid]=xs-(float)xx0;
  }
  __syncthreads();
  const float* fb = (li==0?f2: li==1?f3: li==2?f4: li==3?f5: f6) + (size_t)b*Hl*Wl*256;
  int c = tid;
  for (int cell=0; cell<49; ++cell){
    int cy=cell/7, cx=cell%7;
    float accv=0.f;
    #pragma unroll
    for (int sy=0;sy<2;sy++){
      int iy=cy*2+sy;
      float wy=swy[iy];
      const float* r0 = fb + (size_t)sy0[iy]*Wl*256;
      const float* r1 = fb + (size_t)sy1[iy]*Wl*256;
      #pragma unroll
      for (int sx=0;sx<2;sx++){
        int ix=cx*2+sx;
        float wx=swx[ix];
        int xa=sx0[ix]*256+c, xb=sx1[ix]*256+c;
        float v00=r0[xa], v01=r0[xb], v10=r1[xa], v11=r1[xb];
        accv += v00*(1.f-wy)*(1.f-wx) + v01*(1.f-wy)*wx + v10*wy*(1.f-wx) + v11*wy*wx;
      }
    }
    Arow[cell*256+c] = f2bf(accv*0.25f);
  }
}

// ---------------- bf16 MFMA GEMM: C[M][N] = A[M][K] * BT[N][K]^T ----------------
template<int EPI>
__global__ __launch_bounds__(256) void k_gemm(const u16* __restrict__ A, const u16* __restrict__ BT,
    const float* __restrict__ bias, u16* __restrict__ Hh,
    float* __restrict__ out0, float* __restrict__ out1,
    int K, int nTileN, int nk){
  __shared__ __align__(16) char lds[24576];
  char* ldsA = lds;
  char* ldsB = lds + 16384;
  int bid = blockIdx.x;
  int nwg = gridDim.x;
  int q = nwg >> 3;
  int wgid = (bid & 7)*q + (bid >> 3);
  int mi = wgid / nTileN, ni = wgid % nTileN;
  int m0 = mi*128, n0 = ni*64;
  int tid = threadIdx.x;
  int w = tid >> 6, lane = tid & 63;
  int wm = w >> 1, wn = w & 1;
  int lo4 = lane & 15, hi2 = lane >> 4, xr = lane & 7;
  f32x4 acc[4][2];
  #pragma unroll
  for (int m=0;m<4;m++)
    #pragma unroll
    for (int n=0;n<2;n++) acc[m][n] = (f32x4){0.f,0.f,0.f,0.f};
  int wavebase = tid & ~63;
  for (int kt=0; kt<nk; ++kt){
    const u16* Ak = A + (size_t)kt*64;
    const u16* Bk = BT + (size_t)kt*64;
    #pragma unroll
    for (int c=0;c<4;c++){
      int flat = c*256 + tid;
      int prow = flat >> 3;
      int ls = (flat & 7) ^ (prow & 7);
      stage16(Ak + (size_t)(m0+prow)*K + ls*8, ldsA + (size_t)(c*256 + wavebase)*16);
    }
    #pragma unroll
    for (int c=0;c<2;c++){
      int flat = c*256 + tid;
      int prow = flat >> 3;
      int ls = (flat & 7) ^ (prow & 7);
      stage16(Bk + (size_t)(n0+prow)*K + ls*8, ldsB + (size_t)(c*256 + wavebase)*16);
    }
    __syncthreads();
    bf16x8 af[2][4], bfv[2][2];
    #pragma unroll
    for (int ks=0;ks<2;ks++){
      int sA = (((ks*4 + hi2) ^ xr) << 4);
      #pragma unroll
      for (int m=0;m<4;m++) af[ks][m] = *(const bf16x8*)(ldsA + (wm*64 + m*16 + lo4)*128 + sA);
      #pragma unroll
      for (int n=0;n<2;n++) bfv[ks][n] = *(const bf16x8*)(ldsB + (wn*32 + n*16 + lo4)*128 + sA);
    }
    #pragma unroll
    for (int ks=0;ks<2;ks++)
      #pragma unroll
      for (int m=0;m<4;m++)
        #pragma unroll
        for (int n=0;n<2;n++)
          acc[m][n] = __builtin_amdgcn_mfma_f32_16x16x32_bf16(af[ks][m], bfv[ks][n], acc[m][n], 0,0,0);
    __syncthreads();
  }
  #pragma unroll
  for (int m=0;m<4;m++){
    #pragma unroll
    for (int n=0;n<2;n++){
      int col = n0 + wn*32 + n*16 + lo4;
      float bv = bias[col];
      int rbase = m0 + wm*64 + m*16 + hi2*4;
      #pragma unroll
      for (int j=0;j<4;j++){
        float v = acc[m][n][j] + bv;
        int rr = rbase + j;
        if (EPI == 0){
          v = fmaxf(v, 0.f);
          Hh[(size_t)rr*1024 + col] = f2bf(v);
        } else {
          if (rr < 2000){
            if (col < 91) out0[(size_t)rr*91 + col] = v;
            else if (col < 455) out1[(size_t)rr*364 + (col-91)] = v;
          }
        }
      }
    }
  }
}

extern "C" void kernel_launch(void* const* d_in, const int* in_sizes, int n_in,
                              void* d_out, int out_size, void* d_ws, size_t ws_size,
                              hipStream_t stream) {
  (void)in_sizes; (void)n_in; (void)out_size; (void)ws_size;
  const float *f[5], *s[5], *dl[5], *an[5];
  for (int i=0;i<5;i++){
    f[i]  = (const float*)d_in[4*i+0];
    s[i]  = (const float*)d_in[4*i+1];
    dl[i] = (const float*)d_in[4*i+2];
    an[i] = (const float*)d_in[4*i+3];
  }
  const float* info = (const float*)d_in[20];
  const float* w1 = (const float*)d_in[21];
  const float* b1 = (const float*)d_in[22];
  const float* w2 = (const float*)d_in[23];
  const float* b2 = (const float*)d_in[24];
  const float* wc = (const float*)d_in[25];
  const float* bc = (const float*)d_in[26];
  const float* wb = (const float*)d_in[27];
  const float* bbp= (const float*)d_in[28];

  char* base = (char*)d_ws; size_t off = 0;
  auto alloc = [&](size_t bytes)->char*{ char* p = base + off; off = (off + bytes + 255) & ~(size_t)255; return p; };
  u16*  BT1   = (u16*)alloc(1024ull*12544*2);
  u16*  BT2   = (u16*)alloc(1024ull*1024*2);
  u16*  BT3   = (u16*)alloc(512ull*1024*2);
  float* bias3= (float*)alloc(512*4);
  u16*  Amat  = (u16*)alloc(2048ull*12544*2);
  u16*  h1    = (u16*)alloc(2048ull*1024*2);
  u16*  h2    = (u16*)alloc(2048ull*1024*2);
  u32*  selIdx= (u32*)alloc(9638ull*4);
  float* sRaw = (float*)alloc(9638ull*4);
  float* sPre = (float*)alloc(9638ull*4);
  float* boxes= (float*)alloc(9638ull*16);
  float* allS = (float*)alloc(9638ull*4);
  u64*  masks = (u64*)alloc(9638ull*16*8);
  u32*  histG = (u32*)alloc(10ull*2048*4);
  u32*  cntG  = (u32*)alloc(64);
  u32*  thrG  = (u32*)alloc(64);
  u64*  cand  = (u64*)alloc(10ull*2048*8);

  float* out0 = (float*)d_out;           // (2,1000,91)
  float* out1 = out0 + 182000;           // (2,1000,364)
  float* outR = out0 + 910000;           // (2,1000,4)
  float* outS = out0 + 918000;           // (2,1000)

  k_castT<<<dim3(392,32), dim3(32,8), 0, stream>>>(w1, BT1, 12544, 1024);
  k_castT<<<dim3(32,32),  dim3(32,8), 0, stream>>>(w2, BT2, 1024, 1024);
  k_castW3<<<dim3(2048), dim3(256), 0, stream>>>(wc, wb, bc, bbp, BT3, bias3);

  // ---- top-k (parallelized radix-bin select) ----
  k_zero<<<dim3(82), dim3(256), 0, stream>>>(histG, 10*2048 + 32);   // hist + cnt + thr (contiguous)
  k_hist<<<dim3(640), dim3(256), 0, stream>>>(s[0],s[1],s[2],s[3],s[4], histG);
  k_select<<<dim3(10), dim3(256), 0, stream>>>(histG, thrG);
  k_gather<<<dim3(640), dim3(256), 0, stream>>>(s[0],s[1],s[2],s[3],s[4], thrG, cntG, cand);
  k_sortC<<<dim3(10), dim3(256), 0, stream>>>(cand, cntG, selIdx, sRaw, sPre);

  k_decode<<<dim3(38), dim3(256), 0, stream>>>(selIdx,
      an[0],an[1],an[2],an[3],an[4], dl[0],dl[1],dl[2],dl[3],dl[4], info, boxes);
  k_nms_mask<<<dim3(9638), dim3(256), 0, stream>>>(boxes, masks);
  k_nms_reduce<<<dim3(10), dim3(64), 0, stream>>>(masks, sPre, allS);
  k_final<<<dim3(2), dim3(1024), 0, stream>>>(allS, sRaw, boxes, outR, outS);
  k_roi<<<dim3(2048), dim3(256), 0, stream>>>(outR, f[0],f[1],f[2],f[3],f[4], Amat);
  k_gemm<0><<<dim3(256), dim3(256), 0, stream>>>(Amat, BT1, b1, h1, nullptr, nullptr, 12544, 16, 196);
  k_gemm<0><<<dim3(256), dim3(256), 0, stream>>>(h1,   BT2, b2, h2, nullptr, nullptr, 1024, 16, 16);
  k_gemm<1><<<dim3(128), dim3(256), 0, stream>>>(h2,   BT3, bias3, nullptr, out0, out1, 1024, 8, 16);
}

// Round 4
// 921.549 us; speedup vs baseline: 2.0257x; 1.1894x over previous
//
#include <hip/hip_runtime.h>
#include <hip/hip_bf16.h>
#include <math.h>

typedef unsigned int u32;
typedef unsigned long long u64;
typedef unsigned short u16;
typedef __bf16 bf16x8 __attribute__((ext_vector_type(8)));
typedef float f32x4 __attribute__((ext_vector_type(4)));

#define DEV __device__ __forceinline__

DEV u32 okey(float f){ u32 u=__float_as_uint(f); return (u & 0x80000000u) ? ~u : (u | 0x80000000u); }
DEV float unokey(u32 v){ u32 u = (v & 0x80000000u) ? (v & 0x7FFFFFFFu) : ~v; return __uint_as_float(u); }
DEV u16 f2bf(float f){ u32 u=__float_as_uint(f); u32 r = u + 0x7FFFu + ((u>>16)&1u); return (u16)(r>>16); }

DEV void stage16(const void* g, void* l){
  __builtin_amdgcn_global_load_lds((const __attribute__((address_space(1))) void*)g,
                                   (__attribute__((address_space(3))) void*)l, 16, 0, 0);
}

__constant__ const int c_Nls[5] = {209664,52416,13104,3276,819};
__constant__ const int c_nss[5] = {1000,1000,1000,1000,819};

// ---------------- transpose-cast f32[K][N] -> bf16[N][K] ----------------
__global__ __launch_bounds__(256) void k_castT(const float* __restrict__ src, u16* __restrict__ dst, int K, int N){
  __shared__ float tile[32][33];
  int bk = blockIdx.x, bn = blockIdx.y;
  int tx = threadIdx.x, ty = threadIdx.y;
  #pragma unroll
  for (int i=0;i<4;i++){
    int r = bk*32 + ty + i*8;
    tile[ty+i*8][tx] = src[(size_t)r*N + bn*32 + tx];
  }
  __syncthreads();
  #pragma unroll
  for (int i=0;i<4;i++){
    int n = bn*32 + ty + i*8;
    dst[(size_t)n*K + bk*32 + tx] = f2bf(tile[tx][ty+i*8]);
  }
}

// ------- build BT3 [512][1024] = concat(wc^T, wb^T, 0) and bias3 -------
__global__ __launch_bounds__(256) void k_castW3(const float* __restrict__ wc, const float* __restrict__ wb,
    const float* __restrict__ bc, const float* __restrict__ bb,
    u16* __restrict__ BT3, float* __restrict__ bias3){
  int idx = blockIdx.x*256 + threadIdx.x; // 512*1024
  int n = idx >> 10, k = idx & 1023;
  float v = 0.f;
  if (n < 91) v = wc[(size_t)k*91 + n];
  else if (n < 455) v = wb[(size_t)k*364 + (n-91)];
  BT3[(size_t)n*1024 + k] = f2bf(v);
  if (idx < 512){
    float bv = 0.f;
    if (idx < 91) bv = bc[idx]; else if (idx < 455) bv = bb[idx-91];
    bias3[idx] = bv;
  }
}

// ---------------- top-k stage 0: zero hist + counters ----------------
__global__ __launch_bounds__(256) void k_zero(u32* __restrict__ p, int n){
  int i = blockIdx.x*256 + threadIdx.x;
  if (i < n) p[i] = 0u;
}

// ---------------- top-k stage 1: 11-bit histogram, 64 blocks/group ----------------
__global__ __launch_bounds__(256) void k_hist(const float* s2,const float* s3,const float* s4,const float* s5,const float* s6,
    u32* __restrict__ histG){
  int grp = blockIdx.x >> 6, blk = blockIdx.x & 63;
  int li = grp % 5, b = grp / 5;
  const float* sp = (li==0?s2: li==1?s3: li==2?s4: li==3?s5: s6) + (size_t)b*c_Nls[li];
  int Nl = c_Nls[li];
  __shared__ u32 h[2048];
  int tid = threadIdx.x;
  for (int i=tid;i<2048;i+=256) h[i]=0u;
  __syncthreads();
  for (int i = blk*256 + tid; i < Nl; i += 64*256){
    u32 u = okey(sp[i]);
    atomicAdd(&h[u >> 21], 1u);
  }
  __syncthreads();
  u32* hg = histG + grp*2048;
  for (int i=tid;i<2048;i+=256){ u32 v=h[i]; if (v) atomicAdd(&hg[i], v); }
}

// ---------------- top-k stage 2: find threshold bin ----------------
__global__ __launch_bounds__(256) void k_select(const u32* __restrict__ histG, u32* __restrict__ thrG){
  int grp = blockIdx.x;
  int li = grp % 5;
  u32 ns = (u32)c_nss[li];
  const u32* hg = histG + grp*2048;
  __shared__ u32 part[256];
  int tid = threadIdx.x;
  int hibase = 2047 - tid*8;
  u32 s = 0;
  #pragma unroll
  for (int j=0;j<8;j++) s += hg[hibase - j];
  part[tid] = s;
  __syncthreads();
  if (tid==0){
    u32 cum = 0; int t;
    for (t=0;t<255;t++){ if (cum + part[t] >= ns) break; cum += part[t]; }
    int hb = 2047 - t*8;
    int bin = hb - 7;
    for (int j=0;j<8;j++){ u32 c = hg[hb-j]; if (cum + c >= ns){ bin = hb-j; break; } cum += c; }
    thrG[grp] = (u32)bin;
  }
}

// ---------------- top-k stage 3: gather candidates >= threshold bin ----------------
__global__ __launch_bounds__(256) void k_gather(const float* s2,const float* s3,const float* s4,const float* s5,const float* s6,
    const u32* __restrict__ thrG, u32* __restrict__ cntG, u64* __restrict__ cand){
  int grp = blockIdx.x >> 6, blk = blockIdx.x & 63;
  int li = grp % 5, b = grp / 5;
  const float* sp = (li==0?s2: li==1?s3: li==2?s4: li==3?s5: s6) + (size_t)b*c_Nls[li];
  int Nl = c_Nls[li];
  u32 T = thrG[grp] << 21;
  for (int i = blk*256 + threadIdx.x; i < Nl; i += 64*256){
    u32 u = okey(sp[i]);
    if (u >= T){
      u32 pos = atomicAdd(&cntG[grp], 1u);
      if (pos < 2048u) cand[(size_t)grp*2048 + pos] = ((u64)u<<32) | (u32)(~(u32)i);
    }
  }
}

// ---------------- top-k stage 4: bitonic sort candidates, emit ----------------
__global__ __launch_bounds__(256) void k_sortC(const u64* __restrict__ cand, const u32* __restrict__ cntG,
    u32* __restrict__ selIdx, float* __restrict__ sRaw, float* __restrict__ sPre){
  int grp = blockIdx.x;
  int li = grp % 5, b = grp / 5;
  int ns = c_nss[li];
  __shared__ u64 keys[2048];
  int tid = threadIdx.x;
  u32 cnt = cntG[grp]; if (cnt > 2048u) cnt = 2048u;
  for (int i=tid;i<2048;i+=256) keys[i] = (i < (int)cnt) ? cand[(size_t)grp*2048 + i] : 0ull;
  for (int k2=2;k2<=2048;k2<<=1){
    for (int j2=k2>>1;j2>=1;j2>>=1){
      __syncthreads();
      for (int t=tid;t<1024;t+=256){
        int i1 = ((t & ~(j2-1))<<1) | (t & (j2-1));
        int i2 = i1 | j2;
        u64 a=keys[i1], bb2=keys[i2];
        bool asc = (i1 & k2) != 0;
        bool sw = asc ? (a>bb2) : (a<bb2);
        if (sw){ keys[i1]=bb2; keys[i2]=a; }
      }
    }
  }
  __syncthreads();
  int base = b*4819 + li*1000;
  for (int r=tid;r<ns;r+=256){
    u64 kk = keys[r];
    u32 idx = ~((u32)kk);
    float scv = unokey((u32)(kk>>32));
    selIdx[base+r] = idx;
    sRaw[base+r] = scv;
    sPre[base+r] = (float)(1.0/(1.0+exp(-(double)scv)));
  }
}

// ---------------- decode + clip selected boxes ----------------
__global__ __launch_bounds__(256) void k_decode(const u32* __restrict__ selIdx,
    const float* a2,const float* a3,const float* a4,const float* a5,const float* a6,
    const float* d2,const float* d3,const float* d4,const float* d5,const float* d6,
    const float* __restrict__ info, float* __restrict__ boxes){
  int g = blockIdx.x*256 + threadIdx.x;
  if (g >= 9638) return;
  int b = g/4819, r = g%4819;
  int li = r/1000; if (li>4) li=4;
  u32 idx = selIdx[g];
  const float* anc = li==0?a2: li==1?a3: li==2?a4: li==3?a5: a6;
  const float* del = li==0?d2: li==1?d3: li==2?d4: li==3?d5: d6;
  const float* aa = anc + (size_t)idx*4;
  const float* dd = del + ((size_t)b*c_Nls[li] + idx)*4;
  float ah=aa[2]-aa[0], aw=aa[3]-aa[1];
  float acy=aa[0]+0.5f*ah, acx=aa[1]+0.5f*aw;
  const float CLIPV = 4.135166556742356f;
  float dh=fminf(dd[2],CLIPV), dw=fminf(dd[3],CLIPV);
  float cy=acy+dd[0]*ah, cx=acx+dd[1]*aw;
  float hh=ah*expf(dh), ww=aw*expf(dw);
  float hmax=info[b*5+0], wmax=info[b*5+1];
  float vy1=fminf(fmaxf(cy-0.5f*hh,0.f),hmax);
  float vx1=fminf(fmaxf(cx-0.5f*ww,0.f),wmax);
  float vy2=fminf(fmaxf(cy+0.5f*hh,0.f),hmax);
  float vx2=fminf(fmaxf(cx+0.5f*ww,0.f),wmax);
  ((float4*)boxes)[g] = make_float4(vy1,vx1,vy2,vx2);
}

// ---------------- NMS suppression bitmask matrix ----------------
__global__ __launch_bounds__(256) void k_nms_mask(const float* __restrict__ boxes, u64* __restrict__ masks){
  int rg = blockIdx.x;
  int b = rg/4819, r = rg%4819;
  int li = r/1000; if (li>4) li=4;
  int i = r - li*1000;
  int n = c_nss[li];
  int gb = b*4819 + li*1000;
  __shared__ float4 sbi;
  if (threadIdx.x==0) sbi = ((const float4*)boxes)[gb+i];
  __syncthreads();
  float4 bi = sbi;
  float ai = fmaxf(bi.z-bi.x,0.f)*fmaxf(bi.w-bi.y,0.f);
  int t = threadIdx.x, wv = t>>6, lane = t&63;
  #pragma unroll
  for (int it=0; it<4; ++it){
    int jj = it*256 + wv*64 + lane;
    bool c = false;
    if (jj < n && jj > i){
      float4 bj = ((const float4*)boxes)[gb+jj];
      float aj = fmaxf(bj.z-bj.x,0.f)*fmaxf(bj.w-bj.y,0.f);
      float yy1=fmaxf(bi.x,bj.x), xx1=fmaxf(bi.y,bj.y);
      float yy2=fminf(bi.z,bj.z), xx2=fminf(bi.w,bj.w);
      float inter=fmaxf(yy2-yy1,0.f)*fmaxf(xx2-xx1,0.f);
      float iou = inter/(ai+aj-inter+1e-8f);
      c = iou > 0.7f;
    }
    u64 m = __ballot(c);
    if (lane==0) masks[(size_t)rg*16 + it*4 + wv] = m;
  }
}

// ---------------- serial greedy reduce: pivot-word replication + 4-deep prefetch ----------------
// Per row i: kept-test reads only bit i of `removed` (word i>>6, constant per 64-row span).
// All lanes keep a replicated copy (rpiv) of that word; each row's pivot word is loaded at a
// wave-uniform address (broadcast). Serial chain per row = bit-test + 2 conditional ORs.
// One u64 shfl per 64-row span boundary resyncs rpiv from the distributed `removed`.
__global__ __launch_bounds__(64) void k_nms_reduce(const u64* __restrict__ masks, const float* __restrict__ sPre, float* __restrict__ allS){
  int li = blockIdx.x % 5, b = blockIdx.x / 5;
  int n = c_nss[li];
  int gb = b*4819 + li*1000;
  int lane = threadIdx.x;
  bool ld = lane < 16;
  const u64* mrow = masks + (size_t)gb*16;
  u64 removed = 0ull, rpiv = 0ull;

  u64 ownA[8], pivA[8], ownB[8], pivB[8], ownC[8], pivC[8], ownD[8], pivD[8];

#define LOADC(c0, own, piv) do{ \
  _Pragma("unroll") \
  for (int r_=0;r_<8;r_++){ \
    int i_=(c0)*8+r_; \
    bool ok_ = i_<n; \
    own[r_] = (ok_&&ld) ? mrow[(size_t)i_*16 + lane] : 0ull; \
    piv[r_] = ok_ ? mrow[(size_t)i_*16 + (i_>>6)] : 0ull; \
  } }while(0)

#define RESYNC(c0) do{ \
  if (((c0)&7)==0 && (c0)>0 && (c0)*8 < n) rpiv = __shfl(removed, (c0)>>3); \
  }while(0)

#define PROC(c0, own, piv) do{ \
  RESYNC(c0); \
  _Pragma("unroll") \
  for (int r_=0;r_<8;r_++){ \
    int i_=(c0)*8+r_; \
    if (i_<n){ \
      bool kept_ = ((rpiv >> (i_&63)) & 1ull) == 0ull; \
      if (kept_){ removed |= own[r_]; rpiv |= piv[r_]; } \
    } \
  } }while(0)

  int nc = (n+7)>>3;
  LOADC(0, ownA, pivA);
  LOADC(1, ownB, pivB);
  LOADC(2, ownC, pivC);
  LOADC(3, ownD, pivD);
  for (int c=0; c<nc; c+=4){
    PROC(c,   ownA, pivA); LOADC(c+4, ownA, pivA);
    PROC(c+1, ownB, pivB); LOADC(c+5, ownB, pivB);
    PROC(c+2, ownC, pivC); LOADC(c+6, ownC, pivC);
    PROC(c+3, ownD, pivD); LOADC(c+7, ownD, pivD);
  }
#undef LOADC
#undef RESYNC
#undef PROC

  if (lane < 16){
    for (int q=0; q<64; ++q){
      int jj = lane*64 + q;
      if (jj < n){
        bool kp = ((removed >> q) & 1ull) == 0ull;
        allS[gb+jj] = kp ? sPre[gb+jj] : -1.0f;
      }
    }
  }
}

// ---------------- final global top-1000 (sorted), write rois + rs ----------------
__global__ __launch_bounds__(1024) void k_final(const float* __restrict__ allS, const float* __restrict__ sRaw,
   const float* __restrict__ boxes, float* __restrict__ outR, float* __restrict__ outS){
  __shared__ u64 keys[8192];
  int b = blockIdx.x, tid = threadIdx.x;
  for (int e=tid;e<8192;e+=1024){
    u64 kk = 0ull;
    if (e < 4819){
      float v = allS[b*4819+e];
      u32 ie = (~(u32)e) & 0x7FFFFFFFu;
      if (v > -0.5f) kk = (1ull<<63) | ((u64)okey(sRaw[b*4819+e])<<31) | (u64)ie;
      else           kk = (u64)ie;
    }
    keys[e] = kk;
  }
  for (int k2=2;k2<=8192;k2<<=1){
    for (int j2=k2>>1;j2>=1;j2>>=1){
      __syncthreads();
      for (int t=tid;t<4096;t+=1024){
        int i1 = ((t & ~(j2-1))<<1) | (t & (j2-1));
        int i2 = i1 | j2;
        u64 a=keys[i1], bb2=keys[i2];
        bool asc = (i1 & k2) != 0;
        bool sw = asc ? (a>bb2) : (a<bb2);
        if (sw){ keys[i1]=bb2; keys[i2]=a; }
      }
    }
  }
  __syncthreads();
  for (int r=tid;r<1000;r+=1024){
    u64 kk = keys[r];
    u32 ieF = (u32)kk & 0x7FFFFFFFu;
    int e = (int)((~ieF) & 0x7FFFFFFFu);
    outS[b*1000+r] = allS[b*4819+e];
    ((float4*)outR)[b*1000+r] = ((const float4*)boxes)[b*4819+e];
  }
}

// ---------------- ROI align -> bf16 A matrix [2048][12544] ----------------
__global__ __launch_bounds__(256) void k_roi(const float* __restrict__ rois,
    const float* f2,const float* f3,const float* f4,const float* f5,const float* f6,
    u16* __restrict__ Amat){
  constexpr int Hs[5]={208,104,52,26,13};
  constexpr int Wsv[5]={336,168,84,42,21};
  constexpr float strd[5]={4.f,8.f,16.f,32.f,64.f};
  int g = blockIdx.x;
  u16* Arow = Amat + (size_t)g*12544;
  int tid = threadIdx.x;
  if (g >= 2000){
    for (int i=tid;i<12544;i+=256) Arow[i]=0;
    return;
  }
  int b = g/1000;
  const float* box = rois + (size_t)g*4;
  float y1=box[0], x1=box[1], y2=box[2], x2=box[3];
  float area = fmaxf(y2-y1,0.f)*fmaxf(x2-x1,0.f);
  int lvl = (int)floorf(4.f + log2f(sqrtf(area)/224.f + 1e-8f));
  lvl = lvl < 2 ? 2 : (lvl > 6 ? 6 : lvl);
  int li = lvl-2;
  int Hl=Hs[li], Wl=Wsv[li]; float sc=strd[li];
  __shared__ float swy[14], swx[14];
  __shared__ int sy0[14], sy1[14], sx0[14], sx1[14];
  if (tid < 14){
    float t = (float)tid / 13.f;
    float ys = (y1 + (y2-y1)*t)/sc; ys = fminf(fmaxf(ys,0.f),(float)(Hl-1));
    int yy0 = (int)floorf(ys);
    sy0[tid]=yy0; sy1[tid]=(yy0+1>Hl-1)?(Hl-1):(yy0+1); swy[tid]=ys-(float)yy0;
    float xs = (x1 + (x2-x1)*t)/sc; xs = fminf(fmaxf(xs,0.f),(float)(Wl-1));
    int xx0 = (int)floorf(xs);
    sx0[tid]=xx0; sx1[tid]=(xx0+1>Wl-1)?(Wl-1):(xx0+1); swx[tid]=xs-(float)xx0;
  }
  __syncthreads();
  const float* fb = (li==0?f2: li==1?f3: li==2?f4: li==3?f5: f6) + (size_t)b*Hl*Wl*256;
  int c = tid;
  for (int cell=0; cell<49; ++cell){
    int cy=cell/7, cx=cell%7;
    float accv=0.f;
    #pragma unroll
    for (int sy=0;sy<2;sy++){
      int iy=cy*2+sy;
      float wy=swy[iy];
      const float* r0 = fb + (size_t)sy0[iy]*Wl*256;
      const float* r1 = fb + (size_t)sy1[iy]*Wl*256;
      #pragma unroll
      for (int sx=0;sx<2;sx++){
        int ix=cx*2+sx;
        float wx=swx[ix];
        int xa=sx0[ix]*256+c, xb=sx1[ix]*256+c;
        float v00=r0[xa], v01=r0[xb], v10=r1[xa], v11=r1[xb];
        accv += v00*(1.f-wy)*(1.f-wx) + v01*(1.f-wy)*wx + v10*wy*(1.f-wx) + v11*wy*wx;
      }
    }
    Arow[cell*256+c] = f2bf(accv*0.25f);
  }
}

// ---------------- bf16 MFMA GEMM: C[M][N] = A[M][K] * BT[N][K]^T ----------------
template<int EPI>
__global__ __launch_bounds__(256) void k_gemm(const u16* __restrict__ A, const u16* __restrict__ BT,
    const float* __restrict__ bias, u16* __restrict__ Hh,
    float* __restrict__ out0, float* __restrict__ out1,
    int K, int nTileN, int nk){
  __shared__ __align__(16) char lds[24576];
  char* ldsA = lds;
  char* ldsB = lds + 16384;
  int bid = blockIdx.x;
  int nwg = gridDim.x;
  int q = nwg >> 3;
  int wgid = (bid & 7)*q + (bid >> 3);
  int mi = wgid / nTileN, ni = wgid % nTileN;
  int m0 = mi*128, n0 = ni*64;
  int tid = threadIdx.x;
  int w = tid >> 6, lane = tid & 63;
  int wm = w >> 1, wn = w & 1;
  int lo4 = lane & 15, hi2 = lane >> 4, xr = lane & 7;
  f32x4 acc[4][2];
  #pragma unroll
  for (int m=0;m<4;m++)
    #pragma unroll
    for (int n=0;n<2;n++) acc[m][n] = (f32x4){0.f,0.f,0.f,0.f};
  int wavebase = tid & ~63;
  for (int kt=0; kt<nk; ++kt){
    const u16* Ak = A + (size_t)kt*64;
    const u16* Bk = BT + (size_t)kt*64;
    #pragma unroll
    for (int c=0;c<4;c++){
      int flat = c*256 + tid;
      int prow = flat >> 3;
      int ls = (flat & 7) ^ (prow & 7);
      stage16(Ak + (size_t)(m0+prow)*K + ls*8, ldsA + (size_t)(c*256 + wavebase)*16);
    }
    #pragma unroll
    for (int c=0;c<2;c++){
      int flat = c*256 + tid;
      int prow = flat >> 3;
      int ls = (flat & 7) ^ (prow & 7);
      stage16(Bk + (size_t)(n0+prow)*K + ls*8, ldsB + (size_t)(c*256 + wavebase)*16);
    }
    __syncthreads();
    bf16x8 af[2][4], bfv[2][2];
    #pragma unroll
    for (int ks=0;ks<2;ks++){
      int sA = (((ks*4 + hi2) ^ xr) << 4);
      #pragma unroll
      for (int m=0;m<4;m++) af[ks][m] = *(const bf16x8*)(ldsA + (wm*64 + m*16 + lo4)*128 + sA);
      #pragma unroll
      for (int n=0;n<2;n++) bfv[ks][n] = *(const bf16x8*)(ldsB + (wn*32 + n*16 + lo4)*128 + sA);
    }
    #pragma unroll
    for (int ks=0;ks<2;ks++)
      #pragma unroll
      for (int m=0;m<4;m++)
        #pragma unroll
        for (int n=0;n<2;n++)
          acc[m][n] = __builtin_amdgcn_mfma_f32_16x16x32_bf16(af[ks][m], bfv[ks][n], acc[m][n], 0,0,0);
    __syncthreads();
  }
  #pragma unroll
  for (int m=0;m<4;m++){
    #pragma unroll
    for (int n=0;n<2;n++){
      int col = n0 + wn*32 + n*16 + lo4;
      float bv = bias[col];
      int rbase = m0 + wm*64 + m*16 + hi2*4;
      #pragma unroll
      for (int j=0;j<4;j++){
        float v = acc[m][n][j] + bv;
        int rr = rbase + j;
        if (EPI == 0){
          v = fmaxf(v, 0.f);
          Hh[(size_t)rr*1024 + col] = f2bf(v);
        } else {
          if (rr < 2000){
            if (col < 91) out0[(size_t)rr*91 + col] = v;
            else if (col < 455) out1[(size_t)rr*364 + (col-91)] = v;
          }
        }
      }
    }
  }
}

extern "C" void kernel_launch(void* const* d_in, const int* in_sizes, int n_in,
                              void* d_out, int out_size, void* d_ws, size_t ws_size,
                              hipStream_t stream) {
  (void)in_sizes; (void)n_in; (void)out_size; (void)ws_size;
  const float *f[5], *s[5], *dl[5], *an[5];
  for (int i=0;i<5;i++){
    f[i]  = (const float*)d_in[4*i+0];
    s[i]  = (const float*)d_in[4*i+1];
    dl[i] = (const float*)d_in[4*i+2];
    an[i] = (const float*)d_in[4*i+3];
  }
  const float* info = (const float*)d_in[20];
  const float* w1 = (const float*)d_in[21];
  const float* b1 = (const float*)d_in[22];
  const float* w2 = (const float*)d_in[23];
  const float* b2 = (const float*)d_in[24];
  const float* wc = (const float*)d_in[25];
  const float* bc = (const float*)d_in[26];
  const float* wb = (const float*)d_in[27];
  const float* bbp= (const float*)d_in[28];

  char* base = (char*)d_ws; size_t off = 0;
  auto alloc = [&](size_t bytes)->char*{ char* p = base + off; off = (off + bytes + 255) & ~(size_t)255; return p; };
  u16*  BT1   = (u16*)alloc(1024ull*12544*2);
  u16*  BT2   = (u16*)alloc(1024ull*1024*2);
  u16*  BT3   = (u16*)alloc(512ull*1024*2);
  float* bias3= (float*)alloc(512*4);
  u16*  Amat  = (u16*)alloc(2048ull*12544*2);
  u16*  h1    = (u16*)alloc(2048ull*1024*2);
  u16*  h2    = (u16*)alloc(2048ull*1024*2);
  u32*  selIdx= (u32*)alloc(9638ull*4);
  float* sRaw = (float*)alloc(9638ull*4);
  float* sPre = (float*)alloc(9638ull*4);
  float* boxes= (float*)alloc(9638ull*16);
  float* allS = (float*)alloc(9638ull*4);
  u64*  masks = (u64*)alloc(9638ull*16*8);
  u32*  histG = (u32*)alloc(10ull*2048*4);
  u32*  cntG  = (u32*)alloc(64);
  u32*  thrG  = (u32*)alloc(64);
  u64*  cand  = (u64*)alloc(10ull*2048*8);

  float* out0 = (float*)d_out;           // (2,1000,91)
  float* out1 = out0 + 182000;           // (2,1000,364)
  float* outR = out0 + 910000;           // (2,1000,4)
  float* outS = out0 + 918000;           // (2,1000)

  k_castT<<<dim3(392,32), dim3(32,8), 0, stream>>>(w1, BT1, 12544, 1024);
  k_castT<<<dim3(32,32),  dim3(32,8), 0, stream>>>(w2, BT2, 1024, 1024);
  k_castW3<<<dim3(2048), dim3(256), 0, stream>>>(wc, wb, bc, bbp, BT3, bias3);

  // ---- top-k (parallelized radix-bin select) ----
  k_zero<<<dim3(82), dim3(256), 0, stream>>>(histG, 10*2048 + 32);   // hist + cnt + thr (contiguous)
  k_hist<<<dim3(640), dim3(256), 0, stream>>>(s[0],s[1],s[2],s[3],s[4], histG);
  k_select<<<dim3(10), dim3(256), 0, stream>>>(histG, thrG);
  k_gather<<<dim3(640), dim3(256), 0, stream>>>(s[0],s[1],s[2],s[3],s[4], thrG, cntG, cand);
  k_sortC<<<dim3(10), dim3(256), 0, stream>>>(cand, cntG, selIdx, sRaw, sPre);

  k_decode<<<dim3(38), dim3(256), 0, stream>>>(selIdx,
      an[0],an[1],an[2],an[3],an[4], dl[0],dl[1],dl[2],dl[3],dl[4], info, boxes);
  k_nms_mask<<<dim3(9638), dim3(256), 0, stream>>>(boxes, masks);
  k_nms_reduce<<<dim3(10), dim3(64), 0, stream>>>(masks, sPre, allS);
  k_final<<<dim3(2), dim3(1024), 0, stream>>>(allS, sRaw, boxes, outR, outS);
  k_roi<<<dim3(2048), dim3(256), 0, stream>>>(outR, f[0],f[1],f[2],f[3],f[4], Amat);
  k_gemm<0><<<dim3(256), dim3(256), 0, stream>>>(Amat, BT1, b1, h1, nullptr, nullptr, 12544, 16, 196);
  k_gemm<0><<<dim3(256), dim3(256), 0, stream>>>(h1,   BT2, b2, h2, nullptr, nullptr, 1024, 16, 16);
  k_gemm<1><<<dim3(128), dim3(256), 0, stream>>>(h2,   BT3, bias3, nullptr, out0, out1, 1024, 8, 16);
}

// Round 5
// 806.128 us; speedup vs baseline: 2.3157x; 1.1432x over previous
//
#include <hip/hip_runtime.h>
#include <hip/hip_bf16.h>
#include <math.h>

typedef unsigned int u32;
typedef unsigned long long u64;
typedef unsigned short u16;
typedef __bf16 bf16x8 __attribute__((ext_vector_type(8)));
typedef float f32x4 __attribute__((ext_vector_type(4)));

#define DEV __device__ __forceinline__

DEV u32 okey(float f){ u32 u=__float_as_uint(f); return (u & 0x80000000u) ? ~u : (u | 0x80000000u); }
DEV float unokey(u32 v){ u32 u = (v & 0x80000000u) ? (v & 0x7FFFFFFFu) : ~v; return __uint_as_float(u); }
DEV u16 f2bf(float f){ u32 u=__float_as_uint(f); u32 r = u + 0x7FFFu + ((u>>16)&1u); return (u16)(r>>16); }

DEV void stage16(const void* g, void* l){
  __builtin_amdgcn_global_load_lds((const __attribute__((address_space(1))) void*)g,
                                   (__attribute__((address_space(3))) void*)l, 16, 0, 0);
}

__constant__ const int c_Nls[5] = {209664,52416,13104,3276,819};
__constant__ const int c_nss[5] = {1000,1000,1000,1000,819};

// ---------------- transpose-cast f32[K][N] -> bf16[N][K] ----------------
__global__ __launch_bounds__(256) void k_castT(const float* __restrict__ src, u16* __restrict__ dst, int K, int N){
  __shared__ float tile[32][33];
  int bk = blockIdx.x, bn = blockIdx.y;
  int tx = threadIdx.x, ty = threadIdx.y;
  #pragma unroll
  for (int i=0;i<4;i++){
    int r = bk*32 + ty + i*8;
    tile[ty+i*8][tx] = src[(size_t)r*N + bn*32 + tx];
  }
  __syncthreads();
  #pragma unroll
  for (int i=0;i<4;i++){
    int n = bn*32 + ty + i*8;
    dst[(size_t)n*K + bk*32 + tx] = f2bf(tile[tx][ty+i*8]);
  }
}

// ------- build BT3 [512][1024] = concat(wc^T, wb^T, 0) and bias3 -------
__global__ __launch_bounds__(256) void k_castW3(const float* __restrict__ wc, const float* __restrict__ wb,
    const float* __restrict__ bc, const float* __restrict__ bb,
    u16* __restrict__ BT3, float* __restrict__ bias3){
  int idx = blockIdx.x*256 + threadIdx.x; // 512*1024
  int n = idx >> 10, k = idx & 1023;
  float v = 0.f;
  if (n < 91) v = wc[(size_t)k*91 + n];
  else if (n < 455) v = wb[(size_t)k*364 + (n-91)];
  BT3[(size_t)n*1024 + k] = f2bf(v);
  if (idx < 512){
    float bv = 0.f;
    if (idx < 91) bv = bc[idx]; else if (idx < 455) bv = bb[idx-91];
    bias3[idx] = bv;
  }
}

// ---------------- top-k stage 0: zero hist + counters ----------------
__global__ __launch_bounds__(256) void k_zero(u32* __restrict__ p, int n){
  int i = blockIdx.x*256 + threadIdx.x;
  if (i < n) p[i] = 0u;
}

// ---------------- top-k stage 1: 11-bit histogram, 64 blocks/group ----------------
__global__ __launch_bounds__(256) void k_hist(const float* s2,const float* s3,const float* s4,const float* s5,const float* s6,
    u32* __restrict__ histG){
  int grp = blockIdx.x >> 6, blk = blockIdx.x & 63;
  int li = grp % 5, b = grp / 5;
  const float* sp = (li==0?s2: li==1?s3: li==2?s4: li==3?s5: s6) + (size_t)b*c_Nls[li];
  int Nl = c_Nls[li];
  __shared__ u32 h[2048];
  int tid = threadIdx.x;
  for (int i=tid;i<2048;i+=256) h[i]=0u;
  __syncthreads();
  for (int i = blk*256 + tid; i < Nl; i += 64*256){
    u32 u = okey(sp[i]);
    atomicAdd(&h[u >> 21], 1u);
  }
  __syncthreads();
  u32* hg = histG + grp*2048;
  for (int i=tid;i<2048;i+=256){ u32 v=h[i]; if (v) atomicAdd(&hg[i], v); }
}

// ---------------- top-k stage 2: find threshold bin ----------------
__global__ __launch_bounds__(256) void k_select(const u32* __restrict__ histG, u32* __restrict__ thrG){
  int grp = blockIdx.x;
  int li = grp % 5;
  u32 ns = (u32)c_nss[li];
  const u32* hg = histG + grp*2048;
  __shared__ u32 part[256];
  int tid = threadIdx.x;
  int hibase = 2047 - tid*8;
  u32 s = 0;
  #pragma unroll
  for (int j=0;j<8;j++) s += hg[hibase - j];
  part[tid] = s;
  __syncthreads();
  if (tid==0){
    u32 cum = 0; int t;
    for (t=0;t<255;t++){ if (cum + part[t] >= ns) break; cum += part[t]; }
    int hb = 2047 - t*8;
    int bin = hb - 7;
    for (int j=0;j<8;j++){ u32 c = hg[hb-j]; if (cum + c >= ns){ bin = hb-j; break; } cum += c; }
    thrG[grp] = (u32)bin;
  }
}

// ---------------- top-k stage 3: gather candidates >= threshold bin ----------------
__global__ __launch_bounds__(256) void k_gather(const float* s2,const float* s3,const float* s4,const float* s5,const float* s6,
    const u32* __restrict__ thrG, u32* __restrict__ cntG, u64* __restrict__ cand){
  int grp = blockIdx.x >> 6, blk = blockIdx.x & 63;
  int li = grp % 5, b = grp / 5;
  const float* sp = (li==0?s2: li==1?s3: li==2?s4: li==3?s5: s6) + (size_t)b*c_Nls[li];
  int Nl = c_Nls[li];
  u32 T = thrG[grp] << 21;
  for (int i = blk*256 + threadIdx.x; i < Nl; i += 64*256){
    u32 u = okey(sp[i]);
    if (u >= T){
      u32 pos = atomicAdd(&cntG[grp], 1u);
      if (pos < 2048u) cand[(size_t)grp*2048 + pos] = ((u64)u<<32) | (u32)(~(u32)i);
    }
  }
}

// ---------------- top-k stage 4: bitonic sort candidates, emit ----------------
__global__ __launch_bounds__(256) void k_sortC(const u64* __restrict__ cand, const u32* __restrict__ cntG,
    u32* __restrict__ selIdx, float* __restrict__ sRaw, float* __restrict__ sPre){
  int grp = blockIdx.x;
  int li = grp % 5, b = grp / 5;
  int ns = c_nss[li];
  __shared__ u64 keys[2048];
  int tid = threadIdx.x;
  u32 cnt = cntG[grp]; if (cnt > 2048u) cnt = 2048u;
  for (int i=tid;i<2048;i+=256) keys[i] = (i < (int)cnt) ? cand[(size_t)grp*2048 + i] : 0ull;
  for (int k2=2;k2<=2048;k2<<=1){
    for (int j2=k2>>1;j2>=1;j2>>=1){
      __syncthreads();
      for (int t=tid;t<1024;t+=256){
        int i1 = ((t & ~(j2-1))<<1) | (t & (j2-1));
        int i2 = i1 | j2;
        u64 a=keys[i1], bb2=keys[i2];
        bool asc = (i1 & k2) != 0;
        bool sw = asc ? (a>bb2) : (a<bb2);
        if (sw){ keys[i1]=bb2; keys[i2]=a; }
      }
    }
  }
  __syncthreads();
  int base = b*4819 + li*1000;
  for (int r=tid;r<ns;r+=256){
    u64 kk = keys[r];
    u32 idx = ~((u32)kk);
    float scv = unokey((u32)(kk>>32));
    selIdx[base+r] = idx;
    sRaw[base+r] = scv;
    sPre[base+r] = (float)(1.0/(1.0+exp(-(double)scv)));
  }
}

// ---------------- decode + clip selected boxes ----------------
__global__ __launch_bounds__(256) void k_decode(const u32* __restrict__ selIdx,
    const float* a2,const float* a3,const float* a4,const float* a5,const float* a6,
    const float* d2,const float* d3,const float* d4,const float* d5,const float* d6,
    const float* __restrict__ info, float* __restrict__ boxes){
  int g = blockIdx.x*256 + threadIdx.x;
  if (g >= 9638) return;
  int b = g/4819, r = g%4819;
  int li = r/1000; if (li>4) li=4;
  u32 idx = selIdx[g];
  const float* anc = li==0?a2: li==1?a3: li==2?a4: li==3?a5: a6;
  const float* del = li==0?d2: li==1?d3: li==2?d4: li==3?d5: d6;
  const float* aa = anc + (size_t)idx*4;
  const float* dd = del + ((size_t)b*c_Nls[li] + idx)*4;
  float ah=aa[2]-aa[0], aw=aa[3]-aa[1];
  float acy=aa[0]+0.5f*ah, acx=aa[1]+0.5f*aw;
  const float CLIPV = 4.135166556742356f;
  float dh=fminf(dd[2],CLIPV), dw=fminf(dd[3],CLIPV);
  float cy=acy+dd[0]*ah, cx=acx+dd[1]*aw;
  float hh=ah*expf(dh), ww=aw*expf(dw);
  float hmax=info[b*5+0], wmax=info[b*5+1];
  float vy1=fminf(fmaxf(cy-0.5f*hh,0.f),hmax);
  float vx1=fminf(fmaxf(cx-0.5f*ww,0.f),wmax);
  float vy2=fminf(fmaxf(cy+0.5f*hh,0.f),hmax);
  float vx2=fminf(fmaxf(cx+0.5f*ww,0.f),wmax);
  ((float4*)boxes)[g] = make_float4(vy1,vx1,vy2,vx2);
}

// ---------------- NMS suppression bitmask matrix ----------------
__global__ __launch_bounds__(256) void k_nms_mask(const float* __restrict__ boxes, u64* __restrict__ masks){
  int rg = blockIdx.x;
  int b = rg/4819, r = rg%4819;
  int li = r/1000; if (li>4) li=4;
  int i = r - li*1000;
  int n = c_nss[li];
  int gb = b*4819 + li*1000;
  __shared__ float4 sbi;
  if (threadIdx.x==0) sbi = ((const float4*)boxes)[gb+i];
  __syncthreads();
  float4 bi = sbi;
  float ai = fmaxf(bi.z-bi.x,0.f)*fmaxf(bi.w-bi.y,0.f);
  int t = threadIdx.x, wv = t>>6, lane = t&63;
  #pragma unroll
  for (int it=0; it<4; ++it){
    int jj = it*256 + wv*64 + lane;
    bool c = false;
    if (jj < n && jj > i){
      float4 bj = ((const float4*)boxes)[gb+jj];
      float aj = fmaxf(bj.z-bj.x,0.f)*fmaxf(bj.w-bj.y,0.f);
      float yy1=fmaxf(bi.x,bj.x), xx1=fmaxf(bi.y,bj.y);
      float yy2=fminf(bi.z,bj.z), xx2=fminf(bi.w,bj.w);
      float inter=fmaxf(yy2-yy1,0.f)*fmaxf(xx2-xx1,0.f);
      float iou = inter/(ai+aj-inter+1e-8f);
      c = iou > 0.7f;
    }
    u64 m = __ballot(c);
    if (lane==0) masks[(size_t)rg*16 + it*4 + wv] = m;
  }
}

// ---------------- serial greedy reduce: pivot-word replication + 4-deep prefetch ----------------
__global__ __launch_bounds__(64) void k_nms_reduce(const u64* __restrict__ masks, const float* __restrict__ sPre, float* __restrict__ allS){
  int li = blockIdx.x % 5, b = blockIdx.x / 5;
  int n = c_nss[li];
  int gb = b*4819 + li*1000;
  int lane = threadIdx.x;
  bool ld = lane < 16;
  const u64* mrow = masks + (size_t)gb*16;
  u64 removed = 0ull, rpiv = 0ull;

  u64 ownA[8], pivA[8], ownB[8], pivB[8], ownC[8], pivC[8], ownD[8], pivD[8];

#define LOADC(c0, own, piv) do{ \
  _Pragma("unroll") \
  for (int r_=0;r_<8;r_++){ \
    int i_=(c0)*8+r_; \
    bool ok_ = i_<n; \
    own[r_] = (ok_&&ld) ? mrow[(size_t)i_*16 + lane] : 0ull; \
    piv[r_] = ok_ ? mrow[(size_t)i_*16 + (i_>>6)] : 0ull; \
  } }while(0)

#define RESYNC(c0) do{ \
  if (((c0)&7)==0 && (c0)>0 && (c0)*8 < n) rpiv = __shfl(removed, (c0)>>3); \
  }while(0)

#define PROC(c0, own, piv) do{ \
  RESYNC(c0); \
  _Pragma("unroll") \
  for (int r_=0;r_<8;r_++){ \
    int i_=(c0)*8+r_; \
    if (i_<n){ \
      bool kept_ = ((rpiv >> (i_&63)) & 1ull) == 0ull; \
      if (kept_){ removed |= own[r_]; rpiv |= piv[r_]; } \
    } \
  } }while(0)

  int nc = (n+7)>>3;
  LOADC(0, ownA, pivA);
  LOADC(1, ownB, pivB);
  LOADC(2, ownC, pivC);
  LOADC(3, ownD, pivD);
  for (int c=0; c<nc; c+=4){
    PROC(c,   ownA, pivA); LOADC(c+4, ownA, pivA);
    PROC(c+1, ownB, pivB); LOADC(c+5, ownB, pivB);
    PROC(c+2, ownC, pivC); LOADC(c+6, ownC, pivC);
    PROC(c+3, ownD, pivD); LOADC(c+7, ownD, pivD);
  }
#undef LOADC
#undef RESYNC
#undef PROC

  if (lane < 16){
    for (int q=0; q<64; ++q){
      int jj = lane*64 + q;
      if (jj < n){
        bool kp = ((removed >> q) & 1ull) == 0ull;
        allS[gb+jj] = kp ? sPre[gb+jj] : -1.0f;
      }
    }
  }
}

// ---------------- final global top-1000 (sorted), write rois + rs ----------------
__global__ __launch_bounds__(1024) void k_final(const float* __restrict__ allS, const float* __restrict__ sRaw,
   const float* __restrict__ boxes, float* __restrict__ outR, float* __restrict__ outS){
  __shared__ u64 keys[8192];
  int b = blockIdx.x, tid = threadIdx.x;
  for (int e=tid;e<8192;e+=1024){
    u64 kk = 0ull;
    if (e < 4819){
      float v = allS[b*4819+e];
      u32 ie = (~(u32)e) & 0x7FFFFFFFu;
      if (v > -0.5f) kk = (1ull<<63) | ((u64)okey(sRaw[b*4819+e])<<31) | (u64)ie;
      else           kk = (u64)ie;
    }
    keys[e] = kk;
  }
  for (int k2=2;k2<=8192;k2<<=1){
    for (int j2=k2>>1;j2>=1;j2>>=1){
      __syncthreads();
      for (int t=tid;t<4096;t+=1024){
        int i1 = ((t & ~(j2-1))<<1) | (t & (j2-1));
        int i2 = i1 | j2;
        u64 a=keys[i1], bb2=keys[i2];
        bool asc = (i1 & k2) != 0;
        bool sw = asc ? (a>bb2) : (a<bb2);
        if (sw){ keys[i1]=bb2; keys[i2]=a; }
      }
    }
  }
  __syncthreads();
  for (int r=tid;r<1000;r+=1024){
    u64 kk = keys[r];
    u32 ieF = (u32)kk & 0x7FFFFFFFu;
    int e = (int)((~ieF) & 0x7FFFFFFFu);
    outS[b*1000+r] = allS[b*4819+e];
    ((float4*)outR)[b*1000+r] = ((const float4*)boxes)[b*4819+e];
  }
}

// ---------------- ROI align -> bf16 A matrix [2048][12544] ----------------
__global__ __launch_bounds__(256) void k_roi(const float* __restrict__ rois,
    const float* f2,const float* f3,const float* f4,const float* f5,const float* f6,
    u16* __restrict__ Amat){
  constexpr int Hs[5]={208,104,52,26,13};
  constexpr int Wsv[5]={336,168,84,42,21};
  constexpr float strd[5]={4.f,8.f,16.f,32.f,64.f};
  int g = blockIdx.x;
  u16* Arow = Amat + (size_t)g*12544;
  int tid = threadIdx.x;
  if (g >= 2000){
    for (int i=tid;i<12544;i+=256) Arow[i]=0;
    return;
  }
  int b = g/1000;
  const float* box = rois + (size_t)g*4;
  float y1=box[0], x1=box[1], y2=box[2], x2=box[3];
  float area = fmaxf(y2-y1,0.f)*fmaxf(x2-x1,0.f);
  int lvl = (int)floorf(4.f + log2f(sqrtf(area)/224.f + 1e-8f));
  lvl = lvl < 2 ? 2 : (lvl > 6 ? 6 : lvl);
  int li = lvl-2;
  int Hl=Hs[li], Wl=Wsv[li]; float sc=strd[li];
  __shared__ float swy[14], swx[14];
  __shared__ int sy0[14], sy1[14], sx0[14], sx1[14];
  if (tid < 14){
    float t = (float)tid / 13.f;
    float ys = (y1 + (y2-y1)*t)/sc; ys = fminf(fmaxf(ys,0.f),(float)(Hl-1));
    int yy0 = (int)floorf(ys);
    sy0[tid]=yy0; sy1[tid]=(yy0+1>Hl-1)?(Hl-1):(yy0+1); swy[tid]=ys-(float)yy0;
    float xs = (x1 + (x2-x1)*t)/sc; xs = fminf(fmaxf(xs,0.f),(float)(Wl-1));
    int xx0 = (int)floorf(xs);
    sx0[tid]=xx0; sx1[tid]=(xx0+1>Wl-1)?(Wl-1):(xx0+1); swx[tid]=xs-(float)xx0;
  }
  __syncthreads();
  const float* fb = (li==0?f2: li==1?f3: li==2?f4: li==3?f5: f6) + (size_t)b*Hl*Wl*256;
  int c = tid;
  for (int cell=0; cell<49; ++cell){
    int cy=cell/7, cx=cell%7;
    float accv=0.f;
    #pragma unroll
    for (int sy=0;sy<2;sy++){
      int iy=cy*2+sy;
      float wy=swy[iy];
      const float* r0 = fb + (size_t)sy0[iy]*Wl*256;
      const float* r1 = fb + (size_t)sy1[iy]*Wl*256;
      #pragma unroll
      for (int sx=0;sx<2;sx++){
        int ix=cx*2+sx;
        float wx=swx[ix];
        int xa=sx0[ix]*256+c, xb=sx1[ix]*256+c;
        float v00=r0[xa], v01=r0[xb], v10=r1[xa], v11=r1[xb];
        accv += v00*(1.f-wy)*(1.f-wx) + v01*(1.f-wy)*wx + v10*wy*(1.f-wx) + v11*wy*wx;
      }
    }
    Arow[cell*256+c] = f2bf(accv*0.25f);
  }
}

// ---------------- bf16 MFMA GEMM: C[M][N] = A[M][K] * BT[N][K]^T ----------------
template<int EPI>
__global__ __launch_bounds__(256) void k_gemm(const u16* __restrict__ A, const u16* __restrict__ BT,
    const float* __restrict__ bias, u16* __restrict__ Hh,
    float* __restrict__ out0, float* __restrict__ out1,
    int K, int nTileN, int nk){
  __shared__ __align__(16) char lds[24576];
  char* ldsA = lds;
  char* ldsB = lds + 16384;
  int bid = blockIdx.x;
  int nwg = gridDim.x;
  int q = nwg >> 3;
  int wgid = (bid & 7)*q + (bid >> 3);
  int mi = wgid / nTileN, ni = wgid % nTileN;
  int m0 = mi*128, n0 = ni*64;
  int tid = threadIdx.x;
  int w = tid >> 6, lane = tid & 63;
  int wm = w >> 1, wn = w & 1;
  int lo4 = lane & 15, hi2 = lane >> 4, xr = lane & 7;
  f32x4 acc[4][2];
  #pragma unroll
  for (int m=0;m<4;m++)
    #pragma unroll
    for (int n=0;n<2;n++) acc[m][n] = (f32x4){0.f,0.f,0.f,0.f};
  int wavebase = tid & ~63;
  for (int kt=0; kt<nk; ++kt){
    const u16* Ak = A + (size_t)kt*64;
    const u16* Bk = BT + (size_t)kt*64;
    #pragma unroll
    for (int c=0;c<4;c++){
      int flat = c*256 + tid;
      int prow = flat >> 3;
      int ls = (flat & 7) ^ (prow & 7);
      stage16(Ak + (size_t)(m0+prow)*K + ls*8, ldsA + (size_t)(c*256 + wavebase)*16);
    }
    #pragma unroll
    for (int c=0;c<2;c++){
      int flat = c*256 + tid;
      int prow = flat >> 3;
      int ls = (flat & 7) ^ (prow & 7);
      stage16(Bk + (size_t)(n0+prow)*K + ls*8, ldsB + (size_t)(c*256 + wavebase)*16);
    }
    __syncthreads();
    bf16x8 af[2][4], bfv[2][2];
    #pragma unroll
    for (int ks=0;ks<2;ks++){
      int sA = (((ks*4 + hi2) ^ xr) << 4);
      #pragma unroll
      for (int m=0;m<4;m++) af[ks][m] = *(const bf16x8*)(ldsA + (wm*64 + m*16 + lo4)*128 + sA);
      #pragma unroll
      for (int n=0;n<2;n++) bfv[ks][n] = *(const bf16x8*)(ldsB + (wn*32 + n*16 + lo4)*128 + sA);
    }
    #pragma unroll
    for (int ks=0;ks<2;ks++)
      #pragma unroll
      for (int m=0;m<4;m++)
        #pragma unroll
        for (int n=0;n<2;n++)
          acc[m][n] = __builtin_amdgcn_mfma_f32_16x16x32_bf16(af[ks][m], bfv[ks][n], acc[m][n], 0,0,0);
    __syncthreads();
  }
  #pragma unroll
  for (int m=0;m<4;m++){
    #pragma unroll
    for (int n=0;n<2;n++){
      int col = n0 + wn*32 + n*16 + lo4;
      float bv = bias[col];
      int rbase = m0 + wm*64 + m*16 + hi2*4;
      #pragma unroll
      for (int j=0;j<4;j++){
        float v = acc[m][n][j] + bv;
        int rr = rbase + j;
        if (EPI == 0){
          v = fmaxf(v, 0.f);
          Hh[(size_t)rr*1024 + col] = f2bf(v);
        } else {
          if (rr < 2000){
            if (col < 91) out0[(size_t)rr*91 + col] = v;
            else if (col < 455) out1[(size_t)rr*364 + (col-91)] = v;
          }
        }
      }
    }
  }
}

// ---------------- split-K bf16 MFMA GEMM: Cpart[s][M][N] partials, f32 ----------------
// Same tile/staging/MFMA body as k_gemm; grid = NSPLIT * nTileM * nTileN.
__global__ __launch_bounds__(256) void k_gemm_sk(const u16* __restrict__ A, const u16* __restrict__ BT,
    float* __restrict__ Cpart, int K, int nTileN, int nTiles, int nkPer){
  __shared__ __align__(16) char lds[24576];
  char* ldsA = lds;
  char* ldsB = lds + 16384;
  int bid = blockIdx.x;
  int nwg = gridDim.x;
  int q = nwg >> 3;
  int wgid = (bid & 7)*q + (bid >> 3);
  int kidx = wgid / nTiles;
  int rem  = wgid - kidx*nTiles;
  int mi = rem / nTileN, ni = rem % nTileN;
  int m0 = mi*128, n0 = ni*64;
  int kbase = kidx * nkPer * 64;
  int tid = threadIdx.x;
  int w = tid >> 6, lane = tid & 63;
  int wm = w >> 1, wn = w & 1;
  int lo4 = lane & 15, hi2 = lane >> 4, xr = lane & 7;
  f32x4 acc[4][2];
  #pragma unroll
  for (int m=0;m<4;m++)
    #pragma unroll
    for (int n=0;n<2;n++) acc[m][n] = (f32x4){0.f,0.f,0.f,0.f};
  int wavebase = tid & ~63;
  for (int kt=0; kt<nkPer; ++kt){
    const u16* Ak = A + (size_t)(kbase + kt*64);
    const u16* Bk = BT + (size_t)(kbase + kt*64);
    #pragma unroll
    for (int c=0;c<4;c++){
      int flat = c*256 + tid;
      int prow = flat >> 3;
      int ls = (flat & 7) ^ (prow & 7);
      stage16(Ak + (size_t)(m0+prow)*K + ls*8, ldsA + (size_t)(c*256 + wavebase)*16);
    }
    #pragma unroll
    for (int c=0;c<2;c++){
      int flat = c*256 + tid;
      int prow = flat >> 3;
      int ls = (flat & 7) ^ (prow & 7);
      stage16(Bk + (size_t)(n0+prow)*K + ls*8, ldsB + (size_t)(c*256 + wavebase)*16);
    }
    __syncthreads();
    bf16x8 af[2][4], bfv[2][2];
    #pragma unroll
    for (int ks=0;ks<2;ks++){
      int sA = (((ks*4 + hi2) ^ xr) << 4);
      #pragma unroll
      for (int m=0;m<4;m++) af[ks][m] = *(const bf16x8*)(ldsA + (wm*64 + m*16 + lo4)*128 + sA);
      #pragma unroll
      for (int n=0;n<2;n++) bfv[ks][n] = *(const bf16x8*)(ldsB + (wn*32 + n*16 + lo4)*128 + sA);
    }
    #pragma unroll
    for (int ks=0;ks<2;ks++)
      #pragma unroll
      for (int m=0;m<4;m++)
        #pragma unroll
        for (int n=0;n<2;n++)
          acc[m][n] = __builtin_amdgcn_mfma_f32_16x16x32_bf16(af[ks][m], bfv[ks][n], acc[m][n], 0,0,0);
    __syncthreads();
  }
  float* Cp = Cpart + ((size_t)kidx << 21);   // kidx * 2048*1024
  #pragma unroll
  for (int m=0;m<4;m++){
    #pragma unroll
    for (int n=0;n<2;n++){
      int col = n0 + wn*32 + n*16 + lo4;
      int rbase = m0 + wm*64 + m*16 + hi2*4;
      #pragma unroll
      for (int j=0;j<4;j++){
        Cp[(size_t)(rbase+j)*1024 + col] = acc[m][n][j];
      }
    }
  }
}

// ---------------- reduce 4 split-K partials + bias + relu -> bf16 ----------------
__global__ __launch_bounds__(256) void k_redrelu(const float* __restrict__ Cpart,
    const float* __restrict__ bias, u16* __restrict__ Hh){
  int idx = (blockIdx.x*256 + threadIdx.x)*4;   // over 2048*1024
  float4 p0 = *(const float4*)(Cpart + idx);
  float4 p1 = *(const float4*)(Cpart + (1u<<21) + idx);
  float4 p2 = *(const float4*)(Cpart + (2u<<21) + idx);
  float4 p3 = *(const float4*)(Cpart + (3u<<21) + idx);
  float4 bv = *(const float4*)(bias + (idx & 1023));
  ushort4 o;
  o.x = f2bf(fmaxf(p0.x+p1.x+p2.x+p3.x+bv.x, 0.f));
  o.y = f2bf(fmaxf(p0.y+p1.y+p2.y+p3.y+bv.y, 0.f));
  o.z = f2bf(fmaxf(p0.z+p1.z+p2.z+p3.z+bv.z, 0.f));
  o.w = f2bf(fmaxf(p0.w+p1.w+p2.w+p3.w+bv.w, 0.f));
  *(ushort4*)(Hh + idx) = o;
}

extern "C" void kernel_launch(void* const* d_in, const int* in_sizes, int n_in,
                              void* d_out, int out_size, void* d_ws, size_t ws_size,
                              hipStream_t stream) {
  (void)in_sizes; (void)n_in; (void)out_size; (void)ws_size;
  const float *f[5], *s[5], *dl[5], *an[5];
  for (int i=0;i<5;i++){
    f[i]  = (const float*)d_in[4*i+0];
    s[i]  = (const float*)d_in[4*i+1];
    dl[i] = (const float*)d_in[4*i+2];
    an[i] = (const float*)d_in[4*i+3];
  }
  const float* info = (const float*)d_in[20];
  const float* w1 = (const float*)d_in[21];
  const float* b1 = (const float*)d_in[22];
  const float* w2 = (const float*)d_in[23];
  const float* b2 = (const float*)d_in[24];
  const float* wc = (const float*)d_in[25];
  const float* bc = (const float*)d_in[26];
  const float* wb = (const float*)d_in[27];
  const float* bbp= (const float*)d_in[28];

  char* base = (char*)d_ws; size_t off = 0;
  auto alloc = [&](size_t bytes)->char*{ char* p = base + off; off = (off + bytes + 255) & ~(size_t)255; return p; };
  u16*  BT1   = (u16*)alloc(1024ull*12544*2);
  u16*  BT2   = (u16*)alloc(1024ull*1024*2);
  u16*  BT3   = (u16*)alloc(512ull*1024*2);
  float* bias3= (float*)alloc(512*4);
  u16*  Amat  = (u16*)alloc(2048ull*12544*2);
  u16*  h1    = (u16*)alloc(2048ull*1024*2);
  u16*  h2    = (u16*)alloc(2048ull*1024*2);
  u32*  selIdx= (u32*)alloc(9638ull*4);
  float* sRaw = (float*)alloc(9638ull*4);
  float* sPre = (float*)alloc(9638ull*4);
  float* boxes= (float*)alloc(9638ull*16);
  float* allS = (float*)alloc(9638ull*4);
  u64*  masks = (u64*)alloc(9638ull*16*8);
  u32*  histG = (u32*)alloc(10ull*2048*4);
  u32*  cntG  = (u32*)alloc(64);
  u32*  thrG  = (u32*)alloc(64);
  u64*  cand  = (u64*)alloc(10ull*2048*8);
  float* Cpart= (float*)alloc(4ull*2048*1024*4);

  float* out0 = (float*)d_out;           // (2,1000,91)
  float* out1 = out0 + 182000;           // (2,1000,364)
  float* outR = out0 + 910000;           // (2,1000,4)
  float* outS = out0 + 918000;           // (2,1000)

  k_castT<<<dim3(392,32), dim3(32,8), 0, stream>>>(w1, BT1, 12544, 1024);
  k_castT<<<dim3(32,32),  dim3(32,8), 0, stream>>>(w2, BT2, 1024, 1024);
  k_castW3<<<dim3(2048), dim3(256), 0, stream>>>(wc, wb, bc, bbp, BT3, bias3);

  // ---- top-k (parallelized radix-bin select) ----
  k_zero<<<dim3(82), dim3(256), 0, stream>>>(histG, 10*2048 + 32);   // hist + cnt + thr (contiguous)
  k_hist<<<dim3(640), dim3(256), 0, stream>>>(s[0],s[1],s[2],s[3],s[4], histG);
  k_select<<<dim3(10), dim3(256), 0, stream>>>(histG, thrG);
  k_gather<<<dim3(640), dim3(256), 0, stream>>>(s[0],s[1],s[2],s[3],s[4], thrG, cntG, cand);
  k_sortC<<<dim3(10), dim3(256), 0, stream>>>(cand, cntG, selIdx, sRaw, sPre);

  k_decode<<<dim3(38), dim3(256), 0, stream>>>(selIdx,
      an[0],an[1],an[2],an[3],an[4], dl[0],dl[1],dl[2],dl[3],dl[4], info, boxes);
  k_nms_mask<<<dim3(9638), dim3(256), 0, stream>>>(boxes, masks);
  k_nms_reduce<<<dim3(10), dim3(64), 0, stream>>>(masks, sPre, allS);
  k_final<<<dim3(2), dim3(1024), 0, stream>>>(allS, sRaw, boxes, outR, outS);
  k_roi<<<dim3(2048), dim3(256), 0, stream>>>(outR, f[0],f[1],f[2],f[3],f[4], Amat);

  // ---- GEMM1 with split-K=4 (1024 blocks = 4/CU) + fused reduce ----
  k_gemm_sk<<<dim3(1024), dim3(256), 0, stream>>>(Amat, BT1, Cpart, 12544, 16, 256, 49);
  k_redrelu<<<dim3(2048), dim3(256), 0, stream>>>(Cpart, b1, h1);

  k_gemm<0><<<dim3(256), dim3(256), 0, stream>>>(h1,   BT2, b2, h2, nullptr, nullptr, 1024, 16, 16);
  k_gemm<1><<<dim3(128), dim3(256), 0, stream>>>(h2,   BT3, bias3, nullptr, out0, out1, 1024, 8, 16);
}